// Round 8
// baseline (211.490 us; speedup 1.0000x reference)
//
#include <hip/hip_runtime.h>

#define NN 1024
#define NE 65536

typedef short v8s __attribute__((ext_vector_type(8)));
typedef float v4f __attribute__((ext_vector_type(4)));

// ---------------- ws layout (float offsets) ----------------
constexpr size_t OF_SCAL = 0;        // 64
constexpr size_t OF_MMP  = 64;       // 1024
constexpr size_t OF_DEG  = 1088;     // 1024
constexpr size_t OF_OFF  = 2112;     // 1088
constexpr size_t OF_CUR  = 3200;     // 1024
constexpr size_t OF_EIDX = 4224;     // 65536
constexpr size_t OF_MARK = 69760;    // 65536
constexpr size_t OF_X1H  = 135296;   // 131072
constexpr size_t OF_X1L  = 266368;   // 131072
constexpr size_t OF_H2   = 397440;   // 262144
constexpr size_t OF_S2S  = 659584;   // 8192
constexpr size_t OF_S2D  = 667776;   // 8192
constexpr size_t OF_DEN2 = 675968;   // 8192
constexpr size_t OF_EX2  = 684160;   // 524288
constexpr size_t OF_X2   = 1208448;  // 262144
constexpr size_t OF_BCAT = 1470592;  // 16384
constexpr size_t OF_EAB  = 1486976;  // 65536
constexpr size_t OF_WVEC = 1552512;  // 36096
constexpr size_t OF_SRP  = 1588608;  // 128*32*1024 = 4194304
constexpr size_t OF_C0P  = 5782912;  // 141*1024 -> 145408
constexpr size_t OF_SR   = 5928320;  // 32768
constexpr size_t OF_BASE = 5961088;  // 1024
constexpr size_t OF_AH   = 5962112;  // 1064960
constexpr size_t OF_AL   = 7027072;  // 1064960
constexpr size_t OF_BTH  = 8092032;  // 1064960
constexpr size_t OF_BTL  = 9156992;  // 1064960
constexpr size_t OF_HH   = 10221952; // 524288
constexpr size_t OF_HL   = 10746240; // 524288
constexpr size_t OF_W2TH = 11270528; // 32768
constexpr size_t OF_W2TL = 11303296; // 32768
constexpr size_t OF_WC2TH= 11336064; // 524288
constexpr size_t OF_WC2TL= 11860352; // 524288
constexpr size_t OF_P0   = 12384640; // 8 planes x 1048576
// end = 20773248 f ~ 83 MB

__device__ inline unsigned short f2bf(float x){
  unsigned u = __float_as_uint(x);
  unsigned r = u + 0x7fffu + ((u>>16)&1u);
  return (unsigned short)(r>>16);
}
__device__ inline float bf2f(unsigned short h){
  return __uint_as_float(((unsigned)h)<<16);
}

// ---------------- fused minmax + deg zero ----------------
__global__ void k_mm1(const float* __restrict__ dist, float* mnP, float* mxP, int* __restrict__ deg){
  __shared__ float smn[256], smx[256];
  int tid = threadIdx.x;
  if (blockIdx.x < 4) deg[blockIdx.x*256 + tid] = 0;
  float mn = 1e30f, mx = -1e30f;
  for (int i = blockIdx.x*256 + tid; i < NN*NN; i += gridDim.x*256){
    float v = dist[i]; mn = fminf(mn, v); mx = fmaxf(mx, v);
  }
  smn[tid]=mn; smx[tid]=mx; __syncthreads();
  for (int s=128; s>0; s>>=1){
    if (tid<s){ smn[tid]=fminf(smn[tid],smn[tid+s]); smx[tid]=fmaxf(smx[tid],smx[tid+s]); }
    __syncthreads();
  }
  if (tid==0){ mnP[blockIdx.x]=smn[0]; mxP[blockIdx.x]=smx[0]; }
}

// ---------------- fused small work ----------------
__global__ __launch_bounds__(512) void k_misc(const float* mnP, const float* mxP, float* scal,
    const float* W1, const float* We1, const float* as1, const float* ad1, const float* ae1,
    const float* We2, const float* ae2,
    const float* ew, const float* ec, const float* ev,
    const int* wd, const int* cap, const int* veh, const int* stops, float* wvec,
    const float* Wes, float* Bcat){
  int b = blockIdx.x, t = threadIdx.x;
  if (b == 0){
    __shared__ float smn[512], smx[512];
    smn[t]=mnP[t]; smx[t]=mxP[t]; __syncthreads();
    for (int s=256; s>0; s>>=1){
      if (t<s){ smn[t]=fminf(smn[t],smn[t+s]); smx[t]=fmaxf(smx[t],smx[t+s]); }
      __syncthreads();
    }
    if (t==0){ scal[0]=smn[0]; scal[1]=1.0f/(smx[0]-smn[0]); }
  } else if (b == 1){
    if (t < 8){
      float s=0.f, d=0.f, e=0.f, e2=0.f;
      for (int c=0;c<32;c++){
        int i = t*32+c;
        s += W1[i]*as1[i]; d += W1[i]*ad1[i]; e += We1[i]*ae1[i]; e2 += We2[i]*ae2[i];
      }
      scal[16+t]=s; scal[24+t]=d; scal[32+t]=e; scal[40+t]=e2;
    }
  } else if (b == 2){
    for (int m = 32768 + t; m < 35904; m += 512){
      float v = 0.f;
      if (m >= 34816 && m < 34819) v = ew[wd[0]*3 + (m-34816)];
      else if (m >= 34819 && m < 34822) v = ec[cap[0]*3 + (m-34819)];
      else if (m >= 34822 && m < 34825) v = ev[veh[0]*3 + (m-34822)];
      wvec[m] = v;
    }
    __syncthreads();
    wvec[34825 + stops[t]] = 1.0f;     // 512 stops
  } else {
    int idx = (b-3)*512 + t;           // 32 blocks -> 16384
    int k = idx >> 6, r = idx & 63;
    Bcat[idx] = (r < 32) ? Wes[(size_t)k*32 + r] : Wes[(size_t)(256+k)*32 + (r-32)];
  }
}

__global__ void k_edges(const int* __restrict__ ei, const float* __restrict__ markov,
                        float* __restrict__ mark, int* __restrict__ deg){
  int e = blockIdx.x*256 + threadIdx.x;
  if (e >= NE) return;
  int s = ei[e], d = ei[NE+e];
  mark[e] = markov[(size_t)s*NN + d];
  atomicAdd(&deg[d], 1);
}

__global__ void k_scan(const int* deg, int* off, int* cur){
  __shared__ int tmp[NN];
  int t = threadIdx.x;
  tmp[t] = deg[t]; __syncthreads();
  for (int s=1; s<NN; s<<=1){
    int v = (t>=s) ? tmp[t-s] : 0;
    __syncthreads();
    tmp[t] += v;
    __syncthreads();
  }
  int ex = (t==0) ? 0 : tmp[t-1];
  off[t]=ex; cur[t]=ex;
  if (t==NN-1) off[NN]=tmp[NN-1];
}

__global__ void k_fill(const int* __restrict__ ei, int* __restrict__ cur, int* __restrict__ eidxl){
  int e = blockIdx.x*256 + threadIdx.x;
  if (e >= NE) return;
  int d = ei[NE+e];
  int p = atomicAdd(&cur[d], 1);
  eidxl[p] = e;
}

// ---------------- GAT layer 1 collapsed + x1 write (bf16 hi/lo) ----------------
__global__ __launch_bounds__(64) void k_gat1x1(const int* __restrict__ ei, const int* __restrict__ eidxl,
    const int* __restrict__ off, const float* __restrict__ mark, const float* __restrict__ demand,
    const float* __restrict__ scal, const float* __restrict__ W1, const float* __restrict__ b1,
    unsigned short* __restrict__ X1h, unsigned short* __restrict__ X1l){
  int n = blockIdx.x, lane = threadIdx.x;
  int o0 = off[n], o1 = off[n+1];
  float dn = demand[n];
  float cs[8], cd[8], ce[8], mx[8];
  #pragma unroll
  for (int h=0;h<8;h++){ cs[h]=scal[16+h]; cd[h]=scal[24+h]; ce[h]=scal[32+h]; mx[h]=-1e30f; }
  for (int i=o0+lane; i<o1; i+=64){
    int e = eidxl[i]; float ds = demand[ei[e]]; float me = mark[e];
    #pragma unroll
    for (int h=0;h<8;h++){
      float a = ds*cs[h] + dn*cd[h] + me*ce[h];
      a = a < 0.f ? 0.2f*a : a;
      mx[h] = fmaxf(mx[h], a);
    }
  }
  #pragma unroll
  for (int s=32; s>0; s>>=1){
    #pragma unroll
    for (int h=0;h<8;h++) mx[h] = fmaxf(mx[h], __shfl_xor(mx[h], s));
  }
  float se[8], sd_[8];
  #pragma unroll
  for (int h=0;h<8;h++){ se[h]=0.f; sd_[h]=0.f; }
  for (int i=o0+lane; i<o1; i+=64){
    int e = eidxl[i]; float ds = demand[ei[e]]; float me = mark[e];
    #pragma unroll
    for (int h=0;h<8;h++){
      float a = ds*cs[h] + dn*cd[h] + me*ce[h];
      a = a < 0.f ? 0.2f*a : a;
      float ex = expf(a - mx[h]);
      se[h] += ex; sd_[h] += ex*ds;
    }
  }
  #pragma unroll
  for (int s=32; s>0; s>>=1){
    #pragma unroll
    for (int h=0;h<8;h++){ se[h] += __shfl_xor(se[h], s); sd_[h] += __shfl_xor(sd_[h], s); }
  }
  float t1v[8];
  #pragma unroll
  for (int h=0;h<8;h++) t1v[h] = sd_[h] / (se[h] + 1e-16f);
  #pragma unroll
  for (int q=0;q<4;q++){
    int hc = lane + q*64; int h = hc >> 5;
    float v = fmaxf(t1v[h]*W1[hc] + b1[hc], 0.f);
    unsigned short hh = f2bf(v);
    X1h[(size_t)n*256 + hc] = hh;
    X1l[(size_t)n*256 + hc] = f2bf(v - bf2f(hh));
  }
}

// ---------------- generic f32 GEMM (eab, with fused wvec epilogue) ----------------
__global__ __launch_bounds__(256) void gemm64(const float* __restrict__ A, int lda,
    const float* __restrict__ B, int ldb, float* __restrict__ C, int ldc, int K,
    float* __restrict__ wvec, const float* __restrict__ bes){
  __shared__ float As[16][68];
  __shared__ float Bs[16][68];
  int tid = threadIdx.x;
  int tx = tid & 15, ty = tid >> 4;
  int row0 = ty*4, col0 = tx*4;
  int gm = blockIdx.y*64, gn = blockIdx.x*64;
  float acc[4][4] = {};
  for (int k0 = 0; k0 < K; k0 += 16){
    #pragma unroll
    for (int q=0;q<4;q++){
      int idx = tid*4+q; int i = idx>>4, kk = idx&15;
      As[kk][i] = A[(size_t)(gm+i)*lda + k0 + kk];
    }
    #pragma unroll
    for (int q=0;q<4;q++){
      int idx = tid*4+q; int kk = idx>>6, j = idx&63;
      Bs[kk][j] = B[(size_t)(k0+kk)*ldb + gn + j];
    }
    __syncthreads();
    #pragma unroll
    for (int kk=0;kk<16;kk++){
      float a0=As[kk][row0+0], a1=As[kk][row0+1], a2=As[kk][row0+2], a3=As[kk][row0+3];
      float b0=Bs[kk][col0+0], b1=Bs[kk][col0+1], b2=Bs[kk][col0+2], b3=Bs[kk][col0+3];
      acc[0][0]+=a0*b0; acc[0][1]+=a0*b1; acc[0][2]+=a0*b2; acc[0][3]+=a0*b3;
      acc[1][0]+=a1*b0; acc[1][1]+=a1*b1; acc[1][2]+=a1*b2; acc[1][3]+=a1*b3;
      acc[2][0]+=a2*b0; acc[2][1]+=a2*b1; acc[2][2]+=a2*b2; acc[2][3]+=a2*b3;
      acc[3][0]+=a3*b0; acc[3][1]+=a3*b1; acc[3][2]+=a3*b2; acc[3][3]+=a3*b3;
    }
    __syncthreads();
  }
  #pragma unroll
  for (int i=0;i<4;i++){
    #pragma unroll
    for (int j=0;j<4;j++){
      int cc = gn + col0 + j;
      float v = acc[i][j];
      C[(size_t)(gm+row0+i)*ldc + cc] = v;
      if (wvec && cc >= 32){
        wvec[(size_t)(gm+row0+i)*32 + (cc-32)] = v + bes[cc-32];
      }
    }
  }
}

// ---------------- h2 epilogue fused with s2 dots (wave per node) ----------------
__global__ __launch_bounds__(64) void k_fin2s2(const float* __restrict__ P,
    const float* __restrict__ as2, const float* __restrict__ ad2,
    float* __restrict__ h2, float* __restrict__ s2s, float* __restrict__ s2d){
  int n = blockIdx.x, l = threadIdx.x;
  size_t off = (size_t)n*256 + l*4;
  float4 s = make_float4(0.f,0.f,0.f,0.f);
  #pragma unroll
  for (int p=0;p<8;p++){
    float4 v = *reinterpret_cast<const float4*>(P + ((size_t)p<<20) + off);
    s.x+=v.x; s.y+=v.y; s.z+=v.z; s.w+=v.w;
  }
  *reinterpret_cast<float4*>(h2 + off) = s;
  int c = l*4;
  float ss = s.x*as2[c]+s.y*as2[c+1]+s.z*as2[c+2]+s.w*as2[c+3];
  float sd = s.x*ad2[c]+s.y*ad2[c+1]+s.z*ad2[c+2]+s.w*ad2[c+3];
  #pragma unroll
  for (int sft=1; sft<8; sft<<=1){ ss += __shfl_xor(ss, sft); sd += __shfl_xor(sd, sft); }
  if ((l&7)==0){ s2s[n*8 + (l>>3)] = ss; s2d[n*8 + (l>>3)] = sd; }
}

// max + denom + ex2 in one kernel
__global__ __launch_bounds__(64) void k_gat2maxex(const int* __restrict__ ei, const int* __restrict__ eidxl,
    const int* __restrict__ off, const float* __restrict__ mark, const float* __restrict__ s2s,
    const float* __restrict__ s2d, const float* __restrict__ scal,
    float* __restrict__ den, float* __restrict__ ex2){
  int n = blockIdx.x, lane = threadIdx.x;
  int o0 = off[n], o1 = off[n+1];
  float ce[8], sdn[8], mx[8];
  #pragma unroll
  for (int h=0;h<8;h++){ ce[h]=scal[40+h]; sdn[h]=s2d[n*8+h]; mx[h]=-1e30f; }
  for (int i=o0+lane; i<o1; i+=64){
    int e = eidxl[i]; int s = ei[e]; float me = mark[e];
    #pragma unroll
    for (int h=0;h<8;h++){
      float a = s2s[s*8+h] + sdn[h] + me*ce[h];
      a = a < 0.f ? 0.2f*a : a;
      mx[h] = fmaxf(mx[h], a);
    }
  }
  #pragma unroll
  for (int sft=32; sft>0; sft>>=1){
    #pragma unroll
    for (int h=0;h<8;h++) mx[h] = fmaxf(mx[h], __shfl_xor(mx[h], sft));
  }
  float se[8];
  #pragma unroll
  for (int h=0;h<8;h++) se[h]=0.f;
  for (int i=o0+lane; i<o1; i+=64){
    int e = eidxl[i]; int s = ei[e]; float me = mark[e];
    float exv[8];
    #pragma unroll
    for (int h=0;h<8;h++){
      float a = s2s[s*8+h] + sdn[h] + me*ce[h];
      a = a < 0.f ? 0.2f*a : a;
      exv[h] = expf(a - mx[h]);
      se[h] += exv[h];
    }
    #pragma unroll
    for (int h=0;h<8;h++) ex2[(size_t)e*8+h] = exv[h];
  }
  #pragma unroll
  for (int sft=32; sft>0; sft>>=1){
    #pragma unroll
    for (int h=0;h<8;h++) se[h] += __shfl_xor(se[h], sft);
  }
  if (lane==0){
    #pragma unroll
    for (int h=0;h<8;h++) den[n*8+h] = se[h];
  }
}

__global__ __launch_bounds__(256) void k_agg2(const int* __restrict__ ei, const int* __restrict__ eidxl,
    const int* __restrict__ off, const float* __restrict__ ex2, const float* __restrict__ den,
    const float* __restrict__ h2, const float* __restrict__ b2, float* __restrict__ x2){
  __shared__ int eL[64], sL[64];
  __shared__ float cf[64*8];
  int n = blockIdx.x, tid = threadIdx.x, h = tid >> 5;
  int o0 = off[n], o1 = off[n+1];
  float inv = 1.0f/(den[n*8+h] + 1e-16f);
  float acc = 0.f;
  for (int b = o0; b < o1; b += 64){
    int len = min(64, o1 - b);
    __syncthreads();
    if (tid < len){ int e = eidxl[b+tid]; eL[tid]=e; sL[tid]=ei[e]; }
    __syncthreads();
    for (int idx = tid; idx < len*8; idx += 256)
      cf[idx] = ex2[(size_t)eL[idx>>3]*8 + (idx&7)];
    __syncthreads();
    for (int j=0;j<len;j++){
      acc += cf[j*8 + h] * h2[(size_t)sL[j]*256 + tid];
    }
  }
  x2[(size_t)n*256 + tid] = fmaxf(acc*inv + b2[tid], 0.f);
}

// ---------------- streaming pass over Wc1 (256-row chunks, grid 8x141) ----------------
__global__ __launch_bounds__(256) void k_src0(const float* __restrict__ Wc1, const float* __restrict__ wvec,
                                              float* __restrict__ srP, float* __restrict__ c0P){
  __shared__ float c0s[256*4];
  int t = threadIdx.x;
  int kg = t & 31;
  int rg = t >> 5;
  int col = blockIdx.x*128 + kg*4;
  int chunk = blockIdx.y;
  int m0 = chunk*256;
  float sr[4][4];
  #pragma unroll
  for (int u=0;u<4;u++){ sr[u][0]=0.f; sr[u][1]=0.f; sr[u][2]=0.f; sr[u][3]=0.f; }
  float c0a[4] = {0.f,0.f,0.f,0.f};
  for (int jj=0; jj<8; ++jj){
    int rbase = m0 + jj*32 + rg*4;
    #pragma unroll
    for (int u=0;u<4;u++){
      int m = rbase + u;
      float4 w = make_float4(0.f,0.f,0.f,0.f);
      float wv = 0.f;
      if (m < 35849){
        w = *reinterpret_cast<const float4*>(&Wc1[(size_t)m*1024 + col]);
        wv = wvec[m];
      }
      c0a[0] += wv*w.x; c0a[1] += wv*w.y; c0a[2] += wv*w.z; c0a[3] += wv*w.w;
      if (chunk < 128){
        sr[u][0] += w.x; sr[u][1] += w.y; sr[u][2] += w.z; sr[u][3] += w.w;
      }
    }
  }
  if (chunk < 128){
    #pragma unroll
    for (int u=0;u<4;u++){
      int r = rg*4 + u;
      float4 v = make_float4(sr[u][0], sr[u][1], sr[u][2], sr[u][3]);
      *reinterpret_cast<float4*>(&srP[(size_t)(chunk*32 + r)*1024 + col]) = v;
    }
  }
  c0s[t*4+0]=c0a[0]; c0s[t*4+1]=c0a[1]; c0s[t*4+2]=c0a[2]; c0s[t*4+3]=c0a[3];
  __syncthreads();
  if (t < 32){
    float s0=0.f,s1=0.f,s2=0.f,s3=0.f;
    #pragma unroll
    for (int q=0;q<8;q++){
      int b = (t + q*32)*4;
      s0 += c0s[b+0]; s1 += c0s[b+1]; s2 += c0s[b+2]; s3 += c0s[b+3];
    }
    float4 v = make_float4(s0,s1,s2,s3);
    *reinterpret_cast<float4*>(&c0P[(size_t)chunk*1024 + blockIdx.x*128 + t*4]) = v;
  }
}

__global__ void k_stage2(const float* __restrict__ srP, const float* __restrict__ c0P,
                         const float* __restrict__ bc1, float* __restrict__ Sr, float* __restrict__ base){
  int idx = blockIdx.x*256 + threadIdx.x;
  if (idx < 8192){
    int r = idx >> 8, k4 = idx & 255;
    float s0=0.f,s1=0.f,s2=0.f,s3=0.f;
    for (int c=0;c<128;c++){
      float4 v = *reinterpret_cast<const float4*>(&srP[(size_t)(c*32 + r)*1024 + k4*4]);
      s0+=v.x; s1+=v.y; s2+=v.z; s3+=v.w;
    }
    float4 o = make_float4(s0,s1,s2,s3);
    *reinterpret_cast<float4*>(&Sr[(size_t)r*1024 + k4*4]) = o;
  } else if (idx < 8448){
    int k4 = idx - 8192;
    float4 b = *reinterpret_cast<const float4*>(&bc1[k4*4]);
    float s0=b.x, s1=b.y, s2=b.z, s3=b.w;
    for (int c=0;c<141;c++){
      float4 v = *reinterpret_cast<const float4*>(&c0P[(size_t)c*1024 + k4*4]);
      s0+=v.x; s1+=v.y; s2+=v.z; s3+=v.w;
    }
    float4 o = make_float4(s0,s1,s2,s3);
    *reinterpret_cast<float4*>(&base[k4*4]) = o;
  }
}

// ---------------- bf16 conversions ----------------
__global__ void k_cvtA(const float* __restrict__ dist, const float* __restrict__ markov,
                       const float* __restrict__ eab, const float* __restrict__ scal,
                       unsigned short* __restrict__ Ah, unsigned short* __restrict__ Al){
  int k = blockIdx.x*256 + threadIdx.x;
  int i = blockIdx.y;
  if (k >= 2080) return;
  float mn = scal[0], inv = scal[1];
  float v;
  if (k < 1024) v = (dist[(size_t)i*1024 + k] - mn)*inv;
  else if (k < 2048) v = markov[(size_t)i*1024 + (k-1024)];
  else v = eab[(size_t)i*64 + (k-2048)];
  unsigned short h = f2bf(v);
  Ah[(size_t)i*2080 + k] = h;
  Al[(size_t)i*2080 + k] = f2bf(v - bf2f(h));
}

// transpose+convert (generic)
__device__ inline void cvtT_body(const float* __restrict__ src, const float* __restrict__ src2, int k2,
    int lds, int ldt, unsigned short* __restrict__ Th, unsigned short* __restrict__ Tl,
    int k0, int n0, int t){
  __shared__ unsigned short shh[32][65], shl[32][65];
  #pragma unroll
  for (int q=0;q<8;q++){
    int idx = t + q*256;
    int kl = idx >> 6, nl = idx & 63;
    int k = k0 + kl;
    float v = (k < k2) ? src[(size_t)k*lds + n0 + nl] : src2[(size_t)(k-k2)*lds + n0 + nl];
    unsigned short h = f2bf(v);
    shh[kl][nl] = h;
    shl[kl][nl] = f2bf(v - bf2f(h));
  }
  __syncthreads();
  #pragma unroll
  for (int q=0;q<8;q++){
    int idx = t + q*256;
    int nl = idx >> 5, kl = idx & 31;
    Th[(size_t)(n0+nl)*ldt + k0 + kl] = shh[kl][nl];
    Tl[(size_t)(n0+nl)*ldt + k0 + kl] = shl[kl][nl];
  }
}

__global__ void k_cvtT(const float* __restrict__ src, const float* __restrict__ src2, int k2,
                       int lds, int ldt, unsigned short* __restrict__ Th, unsigned short* __restrict__ Tl){
  cvtT_body(src, src2, k2, lds, ldt, Th, Tl, blockIdx.x*32, blockIdx.y*64, threadIdx.x);
}

// combined weight transposes: by<16 -> Wc2 [1024][1024]; by>=16 -> W2 [256][256]
__global__ void k_cvtW(const float* __restrict__ W2, const float* __restrict__ Wc2,
                       unsigned short* __restrict__ W2th, unsigned short* __restrict__ W2tl,
                       unsigned short* __restrict__ Wc2th, unsigned short* __restrict__ Wc2tl){
  int bx = blockIdx.x, by = blockIdx.y;
  if (by < 16){
    cvtT_body(Wc2, Wc2, 1<<30, 1024, 1024, Wc2th, Wc2tl, bx*32, by*64, threadIdx.x);
  } else {
    if (bx >= 8) return;
    cvtT_body(W2, W2, 1<<30, 256, 256, W2th, W2tl, bx*32, (by-16)*64, threadIdx.x);
  }
}

// ---------------- split-bf16 MFMA GEMM, 128x128 tile, split-K planes ----------------
__global__ __launch_bounds__(256) void k_mfma128(
    const unsigned short* __restrict__ Ah, const unsigned short* __restrict__ Al, int lda,
    const unsigned short* __restrict__ Bth, const unsigned short* __restrict__ Btl, int ldb,
    float* __restrict__ Cp, int ldc, int kSteps, int kTot){
  __shared__ __align__(16) unsigned short Ash[128*32], Asl[128*32], Bsh[128*32], Bsl[128*32];
  int t = threadIdx.x;
  int wave = t >> 6, lane = t & 63;
  int wr = wave >> 1, wc = wave & 1;
  int gm = blockIdx.y*128, gn = blockIdx.x*128;
  float* plane = Cp + ((size_t)blockIdx.z << 20);
  int ks0 = blockIdx.z * kSteps;
  int ks1 = ks0 + kSteps; if (ks1 > kTot) ks1 = kTot;

  int kq = lane >> 4;
  int l15 = lane & 15;
  int r0s = t >> 2,        s0s = t & 3;
  int r1s = (t+256) >> 2,  s1s = t & 3;

  v4f acc[4][4];
  #pragma unroll
  for (int i=0;i<4;i++)
    #pragma unroll
    for (int j=0;j<4;j++) acc[i][j] = (v4f){0.f,0.f,0.f,0.f};

  for (int ks = ks0; ks < ks1; ++ks){
    int kb = ks*32;
    const size_t a0 = (size_t)(gm+r0s)*lda + kb + s0s*8;
    const size_t a1 = (size_t)(gm+r1s)*lda + kb + s1s*8;
    const size_t b0 = (size_t)(gn+r0s)*ldb + kb + s0s*8;
    const size_t b1 = (size_t)(gn+r1s)*ldb + kb + s1s*8;
    v8s gah0 = *(const v8s*)(Ah + a0), gah1 = *(const v8s*)(Ah + a1);
    v8s gal0 = *(const v8s*)(Al + a0), gal1 = *(const v8s*)(Al + a1);
    v8s gbh0 = *(const v8s*)(Bth + b0), gbh1 = *(const v8s*)(Bth + b1);
    v8s gbl0 = *(const v8s*)(Btl + b0), gbl1 = *(const v8s*)(Btl + b1);
    __syncthreads();
    int w0 = r0s*32 + ((s0s ^ ((r0s>>1)&3))*8);
    int w1 = r1s*32 + ((s1s ^ ((r1s>>1)&3))*8);
    *(v8s*)(Ash + w0) = gah0;  *(v8s*)(Ash + w1) = gah1;
    *(v8s*)(Asl + w0) = gal0;  *(v8s*)(Asl + w1) = gal1;
    *(v8s*)(Bsh + w0) = gbh0;  *(v8s*)(Bsh + w1) = gbh1;
    *(v8s*)(Bsl + w0) = gbl0;  *(v8s*)(Bsl + w1) = gbl1;
    __syncthreads();
    v8s fbh[4], fbl[4];
    #pragma unroll
    for (int fj=0; fj<4; fj++){
      int cb = wc*64 + fj*16 + l15;
      int boff = cb*32 + ((kq ^ ((cb>>1)&3))*8);
      fbh[fj] = *(v8s*)(Bsh + boff);
      fbl[fj] = *(v8s*)(Bsl + boff);
    }
    #pragma unroll
    for (int fi=0; fi<4; fi++){
      int ra = wr*64 + fi*16 + l15;
      int aoff = ra*32 + ((kq ^ ((ra>>1)&3))*8);
      v8s fah = *(v8s*)(Ash + aoff);
      v8s fal = *(v8s*)(Asl + aoff);
      #pragma unroll
      for (int fj=0; fj<4; fj++){
        acc[fi][fj] = __builtin_amdgcn_mfma_f32_16x16x32_bf16(fah, fbh[fj], acc[fi][fj], 0, 0, 0);
        acc[fi][fj] = __builtin_amdgcn_mfma_f32_16x16x32_bf16(fah, fbl[fj], acc[fi][fj], 0, 0, 0);
        acc[fi][fj] = __builtin_amdgcn_mfma_f32_16x16x32_bf16(fal, fbh[fj], acc[fi][fj], 0, 0, 0);
      }
    }
  }
  int row0 = gm + wr*64 + (lane>>4)*4;
  int col0 = gn + wc*64 + l15;
  #pragma unroll
  for (int fi=0; fi<4; fi++)
    #pragma unroll
    for (int fj=0; fj<4; fj++)
      #pragma unroll
      for (int r=0; r<4; r++)
        plane[(size_t)(row0 + fi*16 + r)*ldc + col0 + fj*16] = acc[fi][fj][r];
}

// ---------------- epilogues (4 planes) ----------------
__global__ void k_fin_hidden(const float* __restrict__ P, const float* __restrict__ base,
                             unsigned short* __restrict__ Hh, unsigned short* __restrict__ Hl){
  int idx = blockIdx.x*256 + threadIdx.x;
  float4 s = *reinterpret_cast<const float4*>(base + ((idx & 255)*4));
  #pragma unroll
  for (int p=0;p<4;p++){
    float4 v = *reinterpret_cast<const float4*>(P + ((size_t)p<<20) + (size_t)idx*4);
    s.x+=v.x; s.y+=v.y; s.z+=v.z; s.w+=v.w;
  }
  float vv[4] = {s.x, s.y, s.z, s.w};
  unsigned short hh[4], hl[4];
  #pragma unroll
  for (int q=0;q<4;q++){
    float x = fmaxf(vv[q], 0.f);
    hh[q] = f2bf(x);
    hl[q] = f2bf(x - bf2f(hh[q]));
  }
  *reinterpret_cast<uint2*>(Hh + (size_t)idx*4) = *reinterpret_cast<uint2*>(hh);
  *reinterpret_cast<uint2*>(Hl + (size_t)idx*4) = *reinterpret_cast<uint2*>(hl);
}

__global__ void k_fin_out(const float* __restrict__ P, const float* __restrict__ bc2,
                          float* __restrict__ out){
  int idx = blockIdx.x*256 + threadIdx.x;
  float4 s = *reinterpret_cast<const float4*>(bc2 + ((idx & 255)*4));
  #pragma unroll
  for (int p=0;p<4;p++){
    float4 v = *reinterpret_cast<const float4*>(P + ((size_t)p<<20) + (size_t)idx*4);
    s.x+=v.x; s.y+=v.y; s.z+=v.z; s.w+=v.w;
  }
  *reinterpret_cast<float4*>(out + (size_t)idx*4) = s;
}

// ---------------- launcher ----------------
extern "C" void kernel_launch(void* const* d_in, const int* in_sizes, int n_in,
                              void* d_out, int out_size, void* d_ws, size_t ws_size,
                              hipStream_t stream){
  const float* dist     = (const float*)d_in[0];
  const int*   stops    = (const int*)  d_in[1];
  const int*   weekday  = (const int*)  d_in[2];
  const int*   vehicles = (const int*)  d_in[3];
  const float* markov   = (const float*)d_in[4];
  const float* demand   = (const float*)d_in[5];
  const int*   capacity = (const int*)  d_in[6];
  const int*   ei       = (const int*)  d_in[7];
  const float* W1  = (const float*)d_in[8];
  const float* We1 = (const float*)d_in[9];
  const float* as1 = (const float*)d_in[10];
  const float* ad1 = (const float*)d_in[11];
  const float* ae1 = (const float*)d_in[12];
  const float* b1  = (const float*)d_in[13];
  const float* W2  = (const float*)d_in[14];
  const float* We2 = (const float*)d_in[15];
  const float* as2 = (const float*)d_in[16];
  const float* ad2 = (const float*)d_in[17];
  const float* ae2 = (const float*)d_in[18];
  const float* b2  = (const float*)d_in[19];
  const float* Wes = (const float*)d_in[20];
  const float* bes = (const float*)d_in[21];
  const float* ew  = (const float*)d_in[22];
  const float* ec  = (const float*)d_in[23];
  const float* ev  = (const float*)d_in[24];
  const float* Wc1 = (const float*)d_in[25];
  const float* bc1 = (const float*)d_in[26];
  const float* Wc2 = (const float*)d_in[27];
  const float* bc2 = (const float*)d_in[28];

  float* W    = (float*)d_ws;
  float* scal = W + OF_SCAL;
  float* mmP  = W + OF_MMP;
  int*   deg  = (int*)(W + OF_DEG);
  int*   off  = (int*)(W + OF_OFF);
  int*   cur  = (int*)(W + OF_CUR);
  int*   eidxl= (int*)(W + OF_EIDX);
  float* mark = W + OF_MARK;
  unsigned short* X1h = (unsigned short*)(W + OF_X1H);
  unsigned short* X1l = (unsigned short*)(W + OF_X1L);
  float* h2   = W + OF_H2;
  float* s2s  = W + OF_S2S;
  float* s2d  = W + OF_S2D;
  float* den2 = W + OF_DEN2;
  float* ex2  = W + OF_EX2;
  float* x2   = W + OF_X2;
  float* Bcat = W + OF_BCAT;
  float* eab  = W + OF_EAB;
  float* wvec = W + OF_WVEC;
  float* srP  = W + OF_SRP;
  float* c0P  = W + OF_C0P;
  float* Sr   = W + OF_SR;
  float* base = W + OF_BASE;
  unsigned short* Ah    = (unsigned short*)(W + OF_AH);
  unsigned short* Al    = (unsigned short*)(W + OF_AL);
  unsigned short* Bth   = (unsigned short*)(W + OF_BTH);
  unsigned short* Btl   = (unsigned short*)(W + OF_BTL);
  unsigned short* Hh    = (unsigned short*)(W + OF_HH);
  unsigned short* Hl    = (unsigned short*)(W + OF_HL);
  unsigned short* W2th  = (unsigned short*)(W + OF_W2TH);
  unsigned short* W2tl  = (unsigned short*)(W + OF_W2TL);
  unsigned short* Wc2th = (unsigned short*)(W + OF_WC2TH);
  unsigned short* Wc2tl = (unsigned short*)(W + OF_WC2TL);
  float* P0   = W + OF_P0;
  float* out  = (float*)d_out;

  k_mm1 <<<dim3(512), dim3(256), 0, stream>>>(dist, mmP, mmP+512, deg);
  k_misc<<<dim3(35), dim3(512), 0, stream>>>(mmP, mmP+512, scal, W1, We1, as1, ad1, ae1, We2, ae2,
                                             ew, ec, ev, weekday, capacity, vehicles, stops, wvec, Wes, Bcat);
  k_cvtW<<<dim3(32,20), dim3(256), 0, stream>>>(W2, Wc2, W2th, W2tl, Wc2th, Wc2tl);
  k_edges<<<dim3(256), dim3(256), 0, stream>>>(ei, markov, mark, deg);
  k_scan<<<dim3(1), dim3(1024), 0, stream>>>(deg, off, cur);
  k_fill<<<dim3(256), dim3(256), 0, stream>>>(ei, cur, eidxl);
  k_gat1x1<<<dim3(1024), dim3(64), 0, stream>>>(ei, eidxl, off, mark, demand, scal, W1, b1, X1h, X1l);
  // h2 = x1 @ W2 : M=1024, N=256, K=256, splitK=8 (128 blocks)
  k_mfma128<<<dim3(2,8,8), dim3(256), 0, stream>>>(X1h, X1l, 256, W2th, W2tl, 256, P0, 256, 1, 8);
  k_fin2s2<<<dim3(1024), dim3(64), 0, stream>>>(P0, as2, ad2, h2, s2s, s2d);
  k_gat2maxex<<<dim3(1024), dim3(64), 0, stream>>>(ei, eidxl, off, mark, s2s, s2d, scal, den2, ex2);
  k_agg2<<<dim3(1024), dim3(256), 0, stream>>>(ei, eidxl, off, ex2, den2, h2, b2, x2);
  gemm64<<<dim3(1,16), dim3(256), 0, stream>>>(x2, 256, Bcat, 64, eab, 64, 256, wvec, bes);
  k_src0<<<dim3(8,141), dim3(256), 0, stream>>>(Wc1, wvec, srP, c0P);
  k_stage2<<<dim3(33), dim3(256), 0, stream>>>(srP, c0P, bc1, Sr, base);
  k_cvtA<<<dim3(9,1024), dim3(256), 0, stream>>>(dist, markov, eab, scal, Ah, Al);
  k_cvtT<<<dim3(65,16), dim3(256), 0, stream>>>(Wc1 + (size_t)32768*1024, Sr, 2048, 1024, 2080, Bth, Btl);
  // hidden = relu(A @ B + base)  (splitK=4)
  k_mfma128<<<dim3(8,8,4), dim3(256), 0, stream>>>(Ah, Al, 2080, Bth, Btl, 2080, P0, 1024, 17, 65);
  k_fin_hidden<<<dim3(1024), dim3(256), 0, stream>>>(P0, base, Hh, Hl);
  // out = hid @ Wc2 + bc2  (splitK=4)
  k_mfma128<<<dim3(8,8,4), dim3(256), 0, stream>>>(Hh, Hl, 1024, Wc2th, Wc2tl, 1024, P0, 1024, 8, 32);
  k_fin_out<<<dim3(1024), dim3(256), 0, stream>>>(P0, bc2, out);
}

// Round 9
// 193.822 us; speedup vs baseline: 1.0912x; 1.0912x over previous
//
#include <hip/hip_runtime.h>

#define NN 1024
#define NE 65536

typedef short v8s __attribute__((ext_vector_type(8)));
typedef float v4f __attribute__((ext_vector_type(4)));

// ---------------- ws layout (float offsets) ----------------
constexpr size_t OF_SCAL = 0;        // 64
constexpr size_t OF_MMP  = 64;       // 1024
constexpr size_t OF_DEG  = 1088;     // 1024
constexpr size_t OF_OFF  = 2112;     // 1088
constexpr size_t OF_CUR  = 3200;     // 1024
constexpr size_t OF_EIDX = 4224;     // 65536
constexpr size_t OF_MARK = 69760;    // 65536
constexpr size_t OF_X1H  = 135296;   // 131072
constexpr size_t OF_X1L  = 266368;   // 131072
constexpr size_t OF_H2   = 397440;   // 262144
constexpr size_t OF_S2S  = 659584;   // 8192
constexpr size_t OF_S2D  = 667776;   // 8192
constexpr size_t OF_DEN2 = 675968;   // 8192
constexpr size_t OF_EX2  = 684160;   // 524288
constexpr size_t OF_X2   = 1208448;  // 262144
constexpr size_t OF_BCAT = 1470592;  // 16384
constexpr size_t OF_EAB  = 1486976;  // 65536
constexpr size_t OF_WVEC = 1552512;  // 36096
constexpr size_t OF_SRP  = 1588608;  // 64*32*1024 = 2097152
constexpr size_t OF_C0P  = 3685760;  // 71*1024 -> 73728
constexpr size_t OF_SR   = 3759488;  // 32768
constexpr size_t OF_BASE = 3792256;  // 1024
constexpr size_t OF_AH   = 3793280;  // 1064960
constexpr size_t OF_AL   = 4858240;
constexpr size_t OF_BTH  = 5923200;
constexpr size_t OF_BTL  = 6988160;
constexpr size_t OF_HH   = 8053120;  // 524288
constexpr size_t OF_HL   = 8577408;
constexpr size_t OF_W2TH = 9101696;  // 32768
constexpr size_t OF_W2TL = 9134464;
constexpr size_t OF_WC2TH= 9167232;  // 524288
constexpr size_t OF_WC2TL= 9691520;
constexpr size_t OF_P0   = 10215808; // 8 planes x 1048576
// end = 18604416 f ~ 74.4 MB

__device__ inline unsigned short f2bf(float x){
  unsigned u = __float_as_uint(x);
  unsigned r = u + 0x7fffu + ((u>>16)&1u);
  return (unsigned short)(r>>16);
}
__device__ inline float bf2f(unsigned short h){
  return __uint_as_float(((unsigned)h)<<16);
}

// ---------------- fused minmax + deg zero ----------------
__global__ void k_mm1(const float* __restrict__ dist, float* mnP, float* mxP, int* __restrict__ deg){
  __shared__ float smn[256], smx[256];
  int tid = threadIdx.x;
  if (blockIdx.x < 4) deg[blockIdx.x*256 + tid] = 0;
  float mn = 1e30f, mx = -1e30f;
  for (int i = blockIdx.x*256 + tid; i < NN*NN; i += gridDim.x*256){
    float v = dist[i]; mn = fminf(mn, v); mx = fmaxf(mx, v);
  }
  smn[tid]=mn; smx[tid]=mx; __syncthreads();
  for (int s=128; s>0; s>>=1){
    if (tid<s){ smn[tid]=fminf(smn[tid],smn[tid+s]); smx[tid]=fmaxf(smx[tid],smx[tid+s]); }
    __syncthreads();
  }
  if (tid==0){ mnP[blockIdx.x]=smn[0]; mxP[blockIdx.x]=smx[0]; }
}

// ---------------- fused small work ----------------
__global__ __launch_bounds__(512) void k_misc(const float* mnP, const float* mxP, float* scal,
    const float* W1, const float* We1, const float* as1, const float* ad1, const float* ae1,
    const float* We2, const float* ae2,
    const float* ew, const float* ec, const float* ev,
    const int* wd, const int* cap, const int* veh, const int* stops, float* wvec,
    const float* Wes, float* Bcat){
  int b = blockIdx.x, t = threadIdx.x;
  if (b == 0){
    __shared__ float smn[512], smx[512];
    smn[t]=mnP[t]; smx[t]=mxP[t]; __syncthreads();
    for (int s=256; s>0; s>>=1){
      if (t<s){ smn[t]=fminf(smn[t],smn[t+s]); smx[t]=fmaxf(smx[t],smx[t+s]); }
      __syncthreads();
    }
    if (t==0){ scal[0]=smn[0]; scal[1]=1.0f/(smx[0]-smn[0]); }
  } else if (b == 1){
    if (t < 8){
      float s=0.f, d=0.f, e=0.f, e2=0.f;
      for (int c=0;c<32;c++){
        int i = t*32+c;
        s += W1[i]*as1[i]; d += W1[i]*ad1[i]; e += We1[i]*ae1[i]; e2 += We2[i]*ae2[i];
      }
      scal[16+t]=s; scal[24+t]=d; scal[32+t]=e; scal[40+t]=e2;
    }
  } else if (b == 2){
    for (int m = 32768 + t; m < 35904; m += 512){
      float v = 0.f;
      if (m >= 34816 && m < 34819) v = ew[wd[0]*3 + (m-34816)];
      else if (m >= 34819 && m < 34822) v = ec[cap[0]*3 + (m-34819)];
      else if (m >= 34822 && m < 34825) v = ev[veh[0]*3 + (m-34822)];
      wvec[m] = v;
    }
    __syncthreads();
    wvec[34825 + stops[t]] = 1.0f;     // 512 stops
  } else {
    int idx = (b-3)*512 + t;           // 32 blocks -> 16384
    int k = idx >> 6, r = idx & 63;
    Bcat[idx] = (r < 32) ? Wes[(size_t)k*32 + r] : Wes[(size_t)(256+k)*32 + (r-32)];
  }
}

__global__ void k_edges(const int* __restrict__ ei, const float* __restrict__ markov,
                        float* __restrict__ mark, int* __restrict__ deg){
  int e = blockIdx.x*256 + threadIdx.x;
  if (e >= NE) return;
  int s = ei[e], d = ei[NE+e];
  mark[e] = markov[(size_t)s*NN + d];
  atomicAdd(&deg[d], 1);
}

__global__ void k_scan(const int* deg, int* off, int* cur){
  __shared__ int tmp[NN];
  int t = threadIdx.x;
  tmp[t] = deg[t]; __syncthreads();
  for (int s=1; s<NN; s<<=1){
    int v = (t>=s) ? tmp[t-s] : 0;
    __syncthreads();
    tmp[t] += v;
    __syncthreads();
  }
  int ex = (t==0) ? 0 : tmp[t-1];
  off[t]=ex; cur[t]=ex;
  if (t==NN-1) off[NN]=tmp[NN-1];
}

__global__ void k_fill(const int* __restrict__ ei, int* __restrict__ cur, int* __restrict__ eidxl){
  int e = blockIdx.x*256 + threadIdx.x;
  if (e >= NE) return;
  int d = ei[NE+e];
  int p = atomicAdd(&cur[d], 1);
  eidxl[p] = e;
}

// ---------------- GAT layer 1 collapsed + x1 write (bf16 hi/lo) ----------------
__global__ __launch_bounds__(64) void k_gat1x1(const int* __restrict__ ei, const int* __restrict__ eidxl,
    const int* __restrict__ off, const float* __restrict__ mark, const float* __restrict__ demand,
    const float* __restrict__ scal, const float* __restrict__ W1, const float* __restrict__ b1,
    unsigned short* __restrict__ X1h, unsigned short* __restrict__ X1l){
  int n = blockIdx.x, lane = threadIdx.x;
  int o0 = off[n], o1 = off[n+1];
  float dn = demand[n];
  float cs[8], cd[8], ce[8], mx[8];
  #pragma unroll
  for (int h=0;h<8;h++){ cs[h]=scal[16+h]; cd[h]=scal[24+h]; ce[h]=scal[32+h]; mx[h]=-1e30f; }
  for (int i=o0+lane; i<o1; i+=64){
    int e = eidxl[i]; float ds = demand[ei[e]]; float me = mark[e];
    #pragma unroll
    for (int h=0;h<8;h++){
      float a = ds*cs[h] + dn*cd[h] + me*ce[h];
      a = a < 0.f ? 0.2f*a : a;
      mx[h] = fmaxf(mx[h], a);
    }
  }
  #pragma unroll
  for (int s=32; s>0; s>>=1){
    #pragma unroll
    for (int h=0;h<8;h++) mx[h] = fmaxf(mx[h], __shfl_xor(mx[h], s));
  }
  float se[8], sd_[8];
  #pragma unroll
  for (int h=0;h<8;h++){ se[h]=0.f; sd_[h]=0.f; }
  for (int i=o0+lane; i<o1; i+=64){
    int e = eidxl[i]; float ds = demand[ei[e]]; float me = mark[e];
    #pragma unroll
    for (int h=0;h<8;h++){
      float a = ds*cs[h] + dn*cd[h] + me*ce[h];
      a = a < 0.f ? 0.2f*a : a;
      float ex = expf(a - mx[h]);
      se[h] += ex; sd_[h] += ex*ds;
    }
  }
  #pragma unroll
  for (int s=32; s>0; s>>=1){
    #pragma unroll
    for (int h=0;h<8;h++){ se[h] += __shfl_xor(se[h], s); sd_[h] += __shfl_xor(sd_[h], s); }
  }
  float t1v[8];
  #pragma unroll
  for (int h=0;h<8;h++) t1v[h] = sd_[h] / (se[h] + 1e-16f);
  #pragma unroll
  for (int q=0;q<4;q++){
    int hc = lane + q*64; int h = hc >> 5;
    float v = fmaxf(t1v[h]*W1[hc] + b1[hc], 0.f);
    unsigned short hh = f2bf(v);
    X1h[(size_t)n*256 + hc] = hh;
    X1l[(size_t)n*256 + hc] = f2bf(v - bf2f(hh));
  }
}

// ---------------- generic f32 GEMM (eab, with fused wvec epilogue) ----------------
__global__ __launch_bounds__(256) void gemm64(const float* __restrict__ A, int lda,
    const float* __restrict__ B, int ldb, float* __restrict__ C, int ldc, int K,
    float* __restrict__ wvec, const float* __restrict__ bes){
  __shared__ float As[16][68];
  __shared__ float Bs[16][68];
  int tid = threadIdx.x;
  int tx = tid & 15, ty = tid >> 4;
  int row0 = ty*4, col0 = tx*4;
  int gm = blockIdx.y*64, gn = blockIdx.x*64;
  float acc[4][4] = {};
  for (int k0 = 0; k0 < K; k0 += 16){
    #pragma unroll
    for (int q=0;q<4;q++){
      int idx = tid*4+q; int i = idx>>4, kk = idx&15;
      As[kk][i] = A[(size_t)(gm+i)*lda + k0 + kk];
    }
    #pragma unroll
    for (int q=0;q<4;q++){
      int idx = tid*4+q; int kk = idx>>6, j = idx&63;
      Bs[kk][j] = B[(size_t)(k0+kk)*ldb + gn + j];
    }
    __syncthreads();
    #pragma unroll
    for (int kk=0;kk<16;kk++){
      float a0=As[kk][row0+0], a1=As[kk][row0+1], a2=As[kk][row0+2], a3=As[kk][row0+3];
      float b0=Bs[kk][col0+0], b1=Bs[kk][col0+1], b2=Bs[kk][col0+2], b3=Bs[kk][col0+3];
      acc[0][0]+=a0*b0; acc[0][1]+=a0*b1; acc[0][2]+=a0*b2; acc[0][3]+=a0*b3;
      acc[1][0]+=a1*b0; acc[1][1]+=a1*b1; acc[1][2]+=a1*b2; acc[1][3]+=a1*b3;
      acc[2][0]+=a2*b0; acc[2][1]+=a2*b1; acc[2][2]+=a2*b2; acc[2][3]+=a2*b3;
      acc[3][0]+=a3*b0; acc[3][1]+=a3*b1; acc[3][2]+=a3*b2; acc[3][3]+=a3*b3;
    }
    __syncthreads();
  }
  #pragma unroll
  for (int i=0;i<4;i++){
    #pragma unroll
    for (int j=0;j<4;j++){
      int cc = gn + col0 + j;
      float v = acc[i][j];
      C[(size_t)(gm+row0+i)*ldc + cc] = v;
      if (wvec && cc >= 32){
        wvec[(size_t)(gm+row0+i)*32 + (cc-32)] = v + bes[cc-32];
      }
    }
  }
}

// ---------------- h2 epilogue fused with s2 dots (wave per node) ----------------
__global__ __launch_bounds__(64) void k_fin2s2(const float* __restrict__ P,
    const float* __restrict__ as2, const float* __restrict__ ad2,
    float* __restrict__ h2, float* __restrict__ s2s, float* __restrict__ s2d){
  int n = blockIdx.x, l = threadIdx.x;
  size_t off = (size_t)n*256 + l*4;
  float4 s = make_float4(0.f,0.f,0.f,0.f);
  #pragma unroll
  for (int p=0;p<8;p++){
    float4 v = *reinterpret_cast<const float4*>(P + ((size_t)p<<20) + off);
    s.x+=v.x; s.y+=v.y; s.z+=v.z; s.w+=v.w;
  }
  *reinterpret_cast<float4*>(h2 + off) = s;
  int c = l*4;
  float ss = s.x*as2[c]+s.y*as2[c+1]+s.z*as2[c+2]+s.w*as2[c+3];
  float sd = s.x*ad2[c]+s.y*ad2[c+1]+s.z*ad2[c+2]+s.w*ad2[c+3];
  #pragma unroll
  for (int sft=1; sft<8; sft<<=1){ ss += __shfl_xor(ss, sft); sd += __shfl_xor(sd, sft); }
  if ((l&7)==0){ s2s[n*8 + (l>>3)] = ss; s2d[n*8 + (l>>3)] = sd; }
}

// max + denom + ex2 in one kernel
__global__ __launch_bounds__(64) void k_gat2maxex(const int* __restrict__ ei, const int* __restrict__ eidxl,
    const int* __restrict__ off, const float* __restrict__ mark, const float* __restrict__ s2s,
    const float* __restrict__ s2d, const float* __restrict__ scal,
    float* __restrict__ den, float* __restrict__ ex2){
  int n = blockIdx.x, lane = threadIdx.x;
  int o0 = off[n], o1 = off[n+1];
  float ce[8], sdn[8], mx[8];
  #pragma unroll
  for (int h=0;h<8;h++){ ce[h]=scal[40+h]; sdn[h]=s2d[n*8+h]; mx[h]=-1e30f; }
  for (int i=o0+lane; i<o1; i+=64){
    int e = eidxl[i]; int s = ei[e]; float me = mark[e];
    #pragma unroll
    for (int h=0;h<8;h++){
      float a = s2s[s*8+h] + sdn[h] + me*ce[h];
      a = a < 0.f ? 0.2f*a : a;
      mx[h] = fmaxf(mx[h], a);
    }
  }
  #pragma unroll
  for (int sft=32; sft>0; sft>>=1){
    #pragma unroll
    for (int h=0;h<8;h++) mx[h] = fmaxf(mx[h], __shfl_xor(mx[h], sft));
  }
  float se[8];
  #pragma unroll
  for (int h=0;h<8;h++) se[h]=0.f;
  for (int i=o0+lane; i<o1; i+=64){
    int e = eidxl[i]; int s = ei[e]; float me = mark[e];
    float exv[8];
    #pragma unroll
    for (int h=0;h<8;h++){
      float a = s2s[s*8+h] + sdn[h] + me*ce[h];
      a = a < 0.f ? 0.2f*a : a;
      exv[h] = expf(a - mx[h]);
      se[h] += exv[h];
    }
    #pragma unroll
    for (int h=0;h<8;h++) ex2[(size_t)e*8+h] = exv[h];
  }
  #pragma unroll
  for (int sft=32; sft>0; sft>>=1){
    #pragma unroll
    for (int h=0;h<8;h++) se[h] += __shfl_xor(se[h], sft);
  }
  if (lane==0){
    #pragma unroll
    for (int h=0;h<8;h++) den[n*8+h] = se[h];
  }
}

__global__ __launch_bounds__(256) void k_agg2(const int* __restrict__ ei, const int* __restrict__ eidxl,
    const int* __restrict__ off, const float* __restrict__ ex2, const float* __restrict__ den,
    const float* __restrict__ h2, const float* __restrict__ b2, float* __restrict__ x2){
  __shared__ int eL[64], sL[64];
  __shared__ float cf[64*8];
  int n = blockIdx.x, tid = threadIdx.x, h = tid >> 5;
  int o0 = off[n], o1 = off[n+1];
  float inv = 1.0f/(den[n*8+h] + 1e-16f);
  float acc = 0.f;
  for (int b = o0; b < o1; b += 64){
    int len = min(64, o1 - b);
    __syncthreads();
    if (tid < len){ int e = eidxl[b+tid]; eL[tid]=e; sL[tid]=ei[e]; }
    __syncthreads();
    for (int idx = tid; idx < len*8; idx += 256)
      cf[idx] = ex2[(size_t)eL[idx>>3]*8 + (idx&7)];
    __syncthreads();
    for (int j=0;j<len;j++){
      acc += cf[j*8 + h] * h2[(size_t)sL[j]*256 + tid];
    }
  }
  x2[(size_t)n*256 + tid] = fmaxf(acc*inv + b2[tid], 0.f);
}

// ---------------- streaming pass over Wc1 (512-row chunks, grid 8x71) ----------------
__global__ __launch_bounds__(256) void k_src0(const float* __restrict__ Wc1, const float* __restrict__ wvec,
                                              float* __restrict__ srP, float* __restrict__ c0P){
  __shared__ float c0s[256*4];
  int t = threadIdx.x;
  int kg = t & 31;
  int rg = t >> 5;
  int col = blockIdx.x*128 + kg*4;
  int chunk = blockIdx.y;
  int m0 = chunk*512;
  float sr[4][4];
  #pragma unroll
  for (int u=0;u<4;u++){ sr[u][0]=0.f; sr[u][1]=0.f; sr[u][2]=0.f; sr[u][3]=0.f; }
  float c0a[4] = {0.f,0.f,0.f,0.f};
  for (int jj=0; jj<16; ++jj){
    int rbase = m0 + jj*32 + rg*4;
    #pragma unroll
    for (int u=0;u<4;u++){
      int m = rbase + u;
      float4 w = make_float4(0.f,0.f,0.f,0.f);
      float wv = 0.f;
      if (m < 35849){
        w = *reinterpret_cast<const float4*>(&Wc1[(size_t)m*1024 + col]);
        wv = wvec[m];
      }
      c0a[0] += wv*w.x; c0a[1] += wv*w.y; c0a[2] += wv*w.z; c0a[3] += wv*w.w;
      if (chunk < 64){
        sr[u][0] += w.x; sr[u][1] += w.y; sr[u][2] += w.z; sr[u][3] += w.w;
      }
    }
  }
  if (chunk < 64){
    #pragma unroll
    for (int u=0;u<4;u++){
      int r = rg*4 + u;
      float4 v = make_float4(sr[u][0], sr[u][1], sr[u][2], sr[u][3]);
      *reinterpret_cast<float4*>(&srP[(size_t)(chunk*32 + r)*1024 + col]) = v;
    }
  }
  c0s[t*4+0]=c0a[0]; c0s[t*4+1]=c0a[1]; c0s[t*4+2]=c0a[2]; c0s[t*4+3]=c0a[3];
  __syncthreads();
  if (t < 32){
    float s0=0.f,s1=0.f,s2=0.f,s3=0.f;
    #pragma unroll
    for (int q=0;q<8;q++){
      int b = (t + q*32)*4;
      s0 += c0s[b+0]; s1 += c0s[b+1]; s2 += c0s[b+2]; s3 += c0s[b+3];
    }
    float4 v = make_float4(s0,s1,s2,s3);
    *reinterpret_cast<float4*>(&c0P[(size_t)chunk*1024 + blockIdx.x*128 + t*4]) = v;
  }
}

__global__ void k_stage2(const float* __restrict__ srP, const float* __restrict__ c0P,
                         const float* __restrict__ bc1, float* __restrict__ Sr, float* __restrict__ base){
  int idx = blockIdx.x*256 + threadIdx.x;
  if (idx < 8192){
    int r = idx >> 8, k4 = idx & 255;
    float s0=0.f,s1=0.f,s2=0.f,s3=0.f;
    for (int c=0;c<64;c++){
      float4 v = *reinterpret_cast<const float4*>(&srP[(size_t)(c*32 + r)*1024 + k4*4]);
      s0+=v.x; s1+=v.y; s2+=v.z; s3+=v.w;
    }
    float4 o = make_float4(s0,s1,s2,s3);
    *reinterpret_cast<float4*>(&Sr[(size_t)r*1024 + k4*4]) = o;
  } else if (idx < 8448){
    int k4 = idx - 8192;
    float4 b = *reinterpret_cast<const float4*>(&bc1[k4*4]);
    float s0=b.x, s1=b.y, s2=b.z, s3=b.w;
    for (int c=0;c<71;c++){
      float4 v = *reinterpret_cast<const float4*>(&c0P[(size_t)c*1024 + k4*4]);
      s0+=v.x; s1+=v.y; s2+=v.z; s3+=v.w;
    }
    float4 o = make_float4(s0,s1,s2,s3);
    *reinterpret_cast<float4*>(&base[k4*4]) = o;
  }
}

// ---------------- bf16 conversions ----------------
__global__ void k_cvtA(const float* __restrict__ dist, const float* __restrict__ markov,
                       const float* __restrict__ eab, const float* __restrict__ scal,
                       unsigned short* __restrict__ Ah, unsigned short* __restrict__ Al){
  int k = blockIdx.x*256 + threadIdx.x;
  int i = blockIdx.y;
  if (k >= 2080) return;
  float mn = scal[0], inv = scal[1];
  float v;
  if (k < 1024) v = (dist[(size_t)i*1024 + k] - mn)*inv;
  else if (k < 2048) v = markov[(size_t)i*1024 + (k-1024)];
  else v = eab[(size_t)i*64 + (k-2048)];
  unsigned short h = f2bf(v);
  Ah[(size_t)i*2080 + k] = h;
  Al[(size_t)i*2080 + k] = f2bf(v - bf2f(h));
}

// transpose+convert (generic)
__device__ inline void cvtT_body(const float* __restrict__ src, const float* __restrict__ src2, int k2,
    int lds, int ldt, unsigned short* __restrict__ Th, unsigned short* __restrict__ Tl,
    int k0, int n0, int t){
  __shared__ unsigned short shh[32][65], shl[32][65];
  #pragma unroll
  for (int q=0;q<8;q++){
    int idx = t + q*256;
    int kl = idx >> 6, nl = idx & 63;
    int k = k0 + kl;
    float v = (k < k2) ? src[(size_t)k*lds + n0 + nl] : src2[(size_t)(k-k2)*lds + n0 + nl];
    unsigned short h = f2bf(v);
    shh[kl][nl] = h;
    shl[kl][nl] = f2bf(v - bf2f(h));
  }
  __syncthreads();
  #pragma unroll
  for (int q=0;q<8;q++){
    int idx = t + q*256;
    int nl = idx >> 5, kl = idx & 31;
    Th[(size_t)(n0+nl)*ldt + k0 + kl] = shh[kl][nl];
    Tl[(size_t)(n0+nl)*ldt + k0 + kl] = shl[kl][nl];
  }
}

__global__ void k_cvtT(const float* __restrict__ src, const float* __restrict__ src2, int k2,
                       int lds, int ldt, unsigned short* __restrict__ Th, unsigned short* __restrict__ Tl){
  cvtT_body(src, src2, k2, lds, ldt, Th, Tl, blockIdx.x*32, blockIdx.y*64, threadIdx.x);
}

// combined weight transposes: by<16 -> Wc2 [1024][1024]; by>=16 -> W2 [256][256]
__global__ void k_cvtW(const float* __restrict__ W2, const float* __restrict__ Wc2,
                       unsigned short* __restrict__ W2th, unsigned short* __restrict__ W2tl,
                       unsigned short* __restrict__ Wc2th, unsigned short* __restrict__ Wc2tl){
  int bx = blockIdx.x, by = blockIdx.y;
  if (by < 16){
    cvtT_body(Wc2, Wc2, 1<<30, 1024, 1024, Wc2th, Wc2tl, bx*32, by*64, threadIdx.x);
  } else {
    if (bx >= 8) return;
    cvtT_body(W2, W2, 1<<30, 256, 256, W2th, W2tl, bx*32, (by-16)*64, threadIdx.x);
  }
}

// ---------------- split-bf16 MFMA GEMM, 128x128 tile, split-K planes ----------------
__global__ __launch_bounds__(256) void k_mfma128(
    const unsigned short* __restrict__ Ah, const unsigned short* __restrict__ Al, int lda,
    const unsigned short* __restrict__ Bth, const unsigned short* __restrict__ Btl, int ldb,
    float* __restrict__ Cp, int ldc, int kSteps, int kTot){
  __shared__ __align__(16) unsigned short Ash[128*32], Asl[128*32], Bsh[128*32], Bsl[128*32];
  int t = threadIdx.x;
  int wave = t >> 6, lane = t & 63;
  int wr = wave >> 1, wc = wave & 1;
  int gm = blockIdx.y*128, gn = blockIdx.x*128;
  float* plane = Cp + ((size_t)blockIdx.z << 20);
  int ks0 = blockIdx.z * kSteps;
  int ks1 = ks0 + kSteps; if (ks1 > kTot) ks1 = kTot;

  int kq = lane >> 4;
  int l15 = lane & 15;
  int r0s = t >> 2,        s0s = t & 3;
  int r1s = (t+256) >> 2,  s1s = t & 3;

  v4f acc[4][4];
  #pragma unroll
  for (int i=0;i<4;i++)
    #pragma unroll
    for (int j=0;j<4;j++) acc[i][j] = (v4f){0.f,0.f,0.f,0.f};

  for (int ks = ks0; ks < ks1; ++ks){
    int kb = ks*32;
    const size_t a0 = (size_t)(gm+r0s)*lda + kb + s0s*8;
    const size_t a1 = (size_t)(gm+r1s)*lda + kb + s1s*8;
    const size_t b0 = (size_t)(gn+r0s)*ldb + kb + s0s*8;
    const size_t b1 = (size_t)(gn+r1s)*ldb + kb + s1s*8;
    v8s gah0 = *(const v8s*)(Ah + a0), gah1 = *(const v8s*)(Ah + a1);
    v8s gal0 = *(const v8s*)(Al + a0), gal1 = *(const v8s*)(Al + a1);
    v8s gbh0 = *(const v8s*)(Bth + b0), gbh1 = *(const v8s*)(Bth + b1);
    v8s gbl0 = *(const v8s*)(Btl + b0), gbl1 = *(const v8s*)(Btl + b1);
    __syncthreads();
    int w0 = r0s*32 + ((s0s ^ ((r0s>>1)&3))*8);
    int w1 = r1s*32 + ((s1s ^ ((r1s>>1)&3))*8);
    *(v8s*)(Ash + w0) = gah0;  *(v8s*)(Ash + w1) = gah1;
    *(v8s*)(Asl + w0) = gal0;  *(v8s*)(Asl + w1) = gal1;
    *(v8s*)(Bsh + w0) = gbh0;  *(v8s*)(Bsh + w1) = gbh1;
    *(v8s*)(Bsl + w0) = gbl0;  *(v8s*)(Bsl + w1) = gbl1;
    __syncthreads();
    v8s fbh[4], fbl[4];
    #pragma unroll
    for (int fj=0; fj<4; fj++){
      int cb = wc*64 + fj*16 + l15;
      int boff = cb*32 + ((kq ^ ((cb>>1)&3))*8);
      fbh[fj] = *(v8s*)(Bsh + boff);
      fbl[fj] = *(v8s*)(Bsl + boff);
    }
    #pragma unroll
    for (int fi=0; fi<4; fi++){
      int ra = wr*64 + fi*16 + l15;
      int aoff = ra*32 + ((kq ^ ((ra>>1)&3))*8);
      v8s fah = *(v8s*)(Ash + aoff);
      v8s fal = *(v8s*)(Asl + aoff);
      #pragma unroll
      for (int fj=0; fj<4; fj++){
        acc[fi][fj] = __builtin_amdgcn_mfma_f32_16x16x32_bf16(fah, fbh[fj], acc[fi][fj], 0, 0, 0);
        acc[fi][fj] = __builtin_amdgcn_mfma_f32_16x16x32_bf16(fah, fbl[fj], acc[fi][fj], 0, 0, 0);
        acc[fi][fj] = __builtin_amdgcn_mfma_f32_16x16x32_bf16(fal, fbh[fj], acc[fi][fj], 0, 0, 0);
      }
    }
  }
  int row0 = gm + wr*64 + (lane>>4)*4;
  int col0 = gn + wc*64 + l15;
  #pragma unroll
  for (int fi=0; fi<4; fi++)
    #pragma unroll
    for (int fj=0; fj<4; fj++)
      #pragma unroll
      for (int r=0; r<4; r++)
        plane[(size_t)(row0 + fi*16 + r)*ldc + col0 + fj*16] = acc[fi][fj][r];
}

// ---------------- epilogues (8 planes) ----------------
__global__ void k_fin_hidden(const float* __restrict__ P, const float* __restrict__ base,
                             unsigned short* __restrict__ Hh, unsigned short* __restrict__ Hl){
  int idx = blockIdx.x*256 + threadIdx.x;
  float4 s = *reinterpret_cast<const float4*>(base + ((idx & 255)*4));
  #pragma unroll
  for (int p=0;p<8;p++){
    float4 v = *reinterpret_cast<const float4*>(P + ((size_t)p<<20) + (size_t)idx*4);
    s.x+=v.x; s.y+=v.y; s.z+=v.z; s.w+=v.w;
  }
  float vv[4] = {s.x, s.y, s.z, s.w};
  unsigned short hh[4], hl[4];
  #pragma unroll
  for (int q=0;q<4;q++){
    float x = fmaxf(vv[q], 0.f);
    hh[q] = f2bf(x);
    hl[q] = f2bf(x - bf2f(hh[q]));
  }
  *reinterpret_cast<uint2*>(Hh + (size_t)idx*4) = *reinterpret_cast<uint2*>(hh);
  *reinterpret_cast<uint2*>(Hl + (size_t)idx*4) = *reinterpret_cast<uint2*>(hl);
}

__global__ void k_fin_out(const float* __restrict__ P, const float* __restrict__ bc2,
                          float* __restrict__ out){
  int idx = blockIdx.x*256 + threadIdx.x;
  float4 s = *reinterpret_cast<const float4*>(bc2 + ((idx & 255)*4));
  #pragma unroll
  for (int p=0;p<8;p++){
    float4 v = *reinterpret_cast<const float4*>(P + ((size_t)p<<20) + (size_t)idx*4);
    s.x+=v.x; s.y+=v.y; s.z+=v.z; s.w+=v.w;
  }
  *reinterpret_cast<float4*>(out + (size_t)idx*4) = s;
}

// ---------------- launcher ----------------
extern "C" void kernel_launch(void* const* d_in, const int* in_sizes, int n_in,
                              void* d_out, int out_size, void* d_ws, size_t ws_size,
                              hipStream_t stream){
  const float* dist     = (const float*)d_in[0];
  const int*   stops    = (const int*)  d_in[1];
  const int*   weekday  = (const int*)  d_in[2];
  const int*   vehicles = (const int*)  d_in[3];
  const float* markov   = (const float*)d_in[4];
  const float* demand   = (const float*)d_in[5];
  const int*   capacity = (const int*)  d_in[6];
  const int*   ei       = (const int*)  d_in[7];
  const float* W1  = (const float*)d_in[8];
  const float* We1 = (const float*)d_in[9];
  const float* as1 = (const float*)d_in[10];
  const float* ad1 = (const float*)d_in[11];
  const float* ae1 = (const float*)d_in[12];
  const float* b1  = (const float*)d_in[13];
  const float* W2  = (const float*)d_in[14];
  const float* We2 = (const float*)d_in[15];
  const float* as2 = (const float*)d_in[16];
  const float* ad2 = (const float*)d_in[17];
  const float* ae2 = (const float*)d_in[18];
  const float* b2  = (const float*)d_in[19];
  const float* Wes = (const float*)d_in[20];
  const float* bes = (const float*)d_in[21];
  const float* ew  = (const float*)d_in[22];
  const float* ec  = (const float*)d_in[23];
  const float* ev  = (const float*)d_in[24];
  const float* Wc1 = (const float*)d_in[25];
  const float* bc1 = (const float*)d_in[26];
  const float* Wc2 = (const float*)d_in[27];
  const float* bc2 = (const float*)d_in[28];

  float* W    = (float*)d_ws;
  float* scal = W + OF_SCAL;
  float* mmP  = W + OF_MMP;
  int*   deg  = (int*)(W + OF_DEG);
  int*   off  = (int*)(W + OF_OFF);
  int*   cur  = (int*)(W + OF_CUR);
  int*   eidxl= (int*)(W + OF_EIDX);
  float* mark = W + OF_MARK;
  unsigned short* X1h = (unsigned short*)(W + OF_X1H);
  unsigned short* X1l = (unsigned short*)(W + OF_X1L);
  float* h2   = W + OF_H2;
  float* s2s  = W + OF_S2S;
  float* s2d  = W + OF_S2D;
  float* den2 = W + OF_DEN2;
  float* ex2  = W + OF_EX2;
  float* x2   = W + OF_X2;
  float* Bcat = W + OF_BCAT;
  float* eab  = W + OF_EAB;
  float* wvec = W + OF_WVEC;
  float* srP  = W + OF_SRP;
  float* c0P  = W + OF_C0P;
  float* Sr   = W + OF_SR;
  float* base = W + OF_BASE;
  unsigned short* Ah    = (unsigned short*)(W + OF_AH);
  unsigned short* Al    = (unsigned short*)(W + OF_AL);
  unsigned short* Bth   = (unsigned short*)(W + OF_BTH);
  unsigned short* Btl   = (unsigned short*)(W + OF_BTL);
  unsigned short* Hh    = (unsigned short*)(W + OF_HH);
  unsigned short* Hl    = (unsigned short*)(W + OF_HL);
  unsigned short* W2th  = (unsigned short*)(W + OF_W2TH);
  unsigned short* W2tl  = (unsigned short*)(W + OF_W2TL);
  unsigned short* Wc2th = (unsigned short*)(W + OF_WC2TH);
  unsigned short* Wc2tl = (unsigned short*)(W + OF_WC2TL);
  float* P0   = W + OF_P0;
  float* out  = (float*)d_out;

  k_mm1 <<<dim3(512), dim3(256), 0, stream>>>(dist, mmP, mmP+512, deg);
  k_misc<<<dim3(35), dim3(512), 0, stream>>>(mmP, mmP+512, scal, W1, We1, as1, ad1, ae1, We2, ae2,
                                             ew, ec, ev, weekday, capacity, vehicles, stops, wvec, Wes, Bcat);
  k_cvtW<<<dim3(32,20), dim3(256), 0, stream>>>(W2, Wc2, W2th, W2tl, Wc2th, Wc2tl);
  k_edges<<<dim3(256), dim3(256), 0, stream>>>(ei, markov, mark, deg);
  k_scan<<<dim3(1), dim3(1024), 0, stream>>>(deg, off, cur);
  k_fill<<<dim3(256), dim3(256), 0, stream>>>(ei, cur, eidxl);
  k_gat1x1<<<dim3(1024), dim3(64), 0, stream>>>(ei, eidxl, off, mark, demand, scal, W1, b1, X1h, X1l);
  // h2 = x1 @ W2 : M=1024, N=256, K=256, splitK=8 (128 blocks)
  k_mfma128<<<dim3(2,8,8), dim3(256), 0, stream>>>(X1h, X1l, 256, W2th, W2tl, 256, P0, 256, 1, 8);
  k_fin2s2<<<dim3(1024), dim3(64), 0, stream>>>(P0, as2, ad2, h2, s2s, s2d);
  k_gat2maxex<<<dim3(1024), dim3(64), 0, stream>>>(ei, eidxl, off, mark, s2s, s2d, scal, den2, ex2);
  k_agg2<<<dim3(1024), dim3(256), 0, stream>>>(ei, eidxl, off, ex2, den2, h2, b2, x2);
  gemm64<<<dim3(1,16), dim3(256), 0, stream>>>(x2, 256, Bcat, 64, eab, 64, 256, wvec, bes);
  k_src0<<<dim3(8,71), dim3(256), 0, stream>>>(Wc1, wvec, srP, c0P);
  k_stage2<<<dim3(33), dim3(256), 0, stream>>>(srP, c0P, bc1, Sr, base);
  k_cvtA<<<dim3(9,1024), dim3(256), 0, stream>>>(dist, markov, eab, scal, Ah, Al);
  k_cvtT<<<dim3(65,16), dim3(256), 0, stream>>>(Wc1 + (size_t)32768*1024, Sr, 2048, 1024, 2080, Bth, Btl);
  // hidden = relu(A @ B + base)  (splitK=8)
  k_mfma128<<<dim3(8,8,8), dim3(256), 0, stream>>>(Ah, Al, 2080, Bth, Btl, 2080, P0, 1024, 9, 65);
  k_fin_hidden<<<dim3(1024), dim3(256), 0, stream>>>(P0, base, Hh, Hl);
  // out = hid @ Wc2 + bc2  (splitK=8)
  k_mfma128<<<dim3(8,8,8), dim3(256), 0, stream>>>(Hh, Hl, 1024, Wc2th, Wc2tl, 1024, P0, 1024, 4, 32);
  k_fin_out<<<dim3(1024), dim3(256), 0, stream>>>(P0, bc2, out);
}

// Round 10
// 185.073 us; speedup vs baseline: 1.1427x; 1.0473x over previous
//
#include <hip/hip_runtime.h>

#define NN 1024
#define NE 65536

typedef short v8s __attribute__((ext_vector_type(8)));
typedef float v4f __attribute__((ext_vector_type(4)));

// ---------------- ws layout (float offsets) ----------------
constexpr size_t OF_SCAL = 0;        // 64
constexpr size_t OF_MMP  = 64;       // 1024
constexpr size_t OF_DEG  = 1088;     // 1024
constexpr size_t OF_OFF  = 2112;     // 1088
constexpr size_t OF_CUR  = 3200;     // 1024
constexpr size_t OF_EIDX = 4224;     // 65536
constexpr size_t OF_MARK = 69760;    // 65536
constexpr size_t OF_X1   = 135296;   // 262144 (f32 x1)
constexpr size_t OF_H2   = 397440;   // 262144
constexpr size_t OF_S2S  = 659584;   // 8192
constexpr size_t OF_S2D  = 667776;   // 8192
constexpr size_t OF_X2   = 675968;   // 262144
constexpr size_t OF_BCAT = 938112;   // 16384
constexpr size_t OF_EAB  = 954496;   // 65536
constexpr size_t OF_WVEC = 1020032;  // 36096
constexpr size_t OF_SRP  = 1056128;  // 64*32*1024 = 2097152
constexpr size_t OF_C0P  = 3153280;  // 71*1024 -> 73728
constexpr size_t OF_SR   = 3227008;  // 32768
constexpr size_t OF_BASE = 3259776;  // 1024
constexpr size_t OF_BTH  = 3260800;  // 1064960
constexpr size_t OF_BTL  = 4325760;  // 1064960
constexpr size_t OF_HID  = 5390720;  // 1048576 (f32 hidden)
constexpr size_t OF_W2TH = 6439296;  // 32768
constexpr size_t OF_W2TL = 6472064;  // 32768
constexpr size_t OF_WC2TH= 6504832;  // 524288
constexpr size_t OF_WC2TL= 7029120;  // 524288
constexpr size_t OF_P0   = 7553408;  // 8 planes x 1048576
// end = 15941984 f ~ 63.8 MB

__device__ inline unsigned short f2bf(float x){
  unsigned u = __float_as_uint(x);
  unsigned r = u + 0x7fffu + ((u>>16)&1u);
  return (unsigned short)(r>>16);
}
__device__ inline float bf2f(unsigned short h){
  return __uint_as_float(((unsigned)h)<<16);
}

// transpose+convert body (256 threads)
__device__ inline void cvtT_body(const float* __restrict__ src, const float* __restrict__ src2, int k2,
    int lds, int ldt, unsigned short* __restrict__ Th, unsigned short* __restrict__ Tl,
    int k0, int n0, int t){
  __shared__ unsigned short shh[32][65], shl[32][65];
  #pragma unroll
  for (int q=0;q<8;q++){
    int idx = t + q*256;
    int kl = idx >> 6, nl = idx & 63;
    int k = k0 + kl;
    float v = (k < k2) ? src[(size_t)k*lds + n0 + nl] : src2[(size_t)(k-k2)*lds + n0 + nl];
    unsigned short h = f2bf(v);
    shh[kl][nl] = h;
    shl[kl][nl] = f2bf(v - bf2f(h));
  }
  __syncthreads();
  #pragma unroll
  for (int q=0;q<8;q++){
    int idx = t + q*256;
    int nl = idx >> 5, kl = idx & 31;
    Th[(size_t)(n0+nl)*ldt + k0 + kl] = shh[kl][nl];
    Tl[(size_t)(n0+nl)*ldt + k0 + kl] = shl[kl][nl];
  }
}

// ---------------- fused: minmax(512 blocks) + deg zero + weight transposes(640 blocks) ----------------
__global__ __launch_bounds__(256) void k_mm1cvtW(const float* __restrict__ dist, float* mnP, float* mxP,
    int* __restrict__ deg, const float* __restrict__ W2, const float* __restrict__ Wc2,
    unsigned short* __restrict__ W2th, unsigned short* __restrict__ W2tl,
    unsigned short* __restrict__ Wc2th, unsigned short* __restrict__ Wc2tl){
  int b = blockIdx.x, tid = threadIdx.x;
  if (b < 512){
    __shared__ float smn[256], smx[256];
    if (b < 4) deg[b*256 + tid] = 0;
    float mn = 1e30f, mx = -1e30f;
    for (int i = b*256 + tid; i < NN*NN; i += 512*256){
      float v = dist[i]; mn = fminf(mn, v); mx = fmaxf(mx, v);
    }
    smn[tid]=mn; smx[tid]=mx; __syncthreads();
    for (int s=128; s>0; s>>=1){
      if (tid<s){ smn[tid]=fminf(smn[tid],smn[tid+s]); smx[tid]=fmaxf(smx[tid],smx[tid+s]); }
      __syncthreads();
    }
    if (tid==0){ mnP[b]=smn[0]; mxP[b]=smx[0]; }
  } else {
    int flat = b - 512;
    int by = flat >> 5, bx = flat & 31;
    if (by < 16){
      cvtT_body(Wc2, Wc2, 1<<30, 1024, 1024, Wc2th, Wc2tl, bx*32, by*64, tid);
    } else {
      if (bx < 8) cvtT_body(W2, W2, 1<<30, 256, 256, W2th, W2tl, bx*32, (by-16)*64, tid);
    }
  }
}

// ---------------- fused small work ----------------
__global__ __launch_bounds__(512) void k_misc(const float* mnP, const float* mxP, float* scal,
    const float* W1, const float* We1, const float* as1, const float* ad1, const float* ae1,
    const float* We2, const float* ae2,
    const float* ew, const float* ec, const float* ev,
    const int* wd, const int* cap, const int* veh, const int* stops, float* wvec,
    const float* Wes, float* Bcat){
  int b = blockIdx.x, t = threadIdx.x;
  if (b == 0){
    __shared__ float smn[512], smx[512];
    smn[t]=mnP[t]; smx[t]=mxP[t]; __syncthreads();
    for (int s=256; s>0; s>>=1){
      if (t<s){ smn[t]=fminf(smn[t],smn[t+s]); smx[t]=fmaxf(smx[t],smx[t+s]); }
      __syncthreads();
    }
    if (t==0){ scal[0]=smn[0]; scal[1]=1.0f/(smx[0]-smn[0]); }
  } else if (b == 1){
    if (t < 8){
      float s=0.f, d=0.f, e=0.f, e2=0.f;
      for (int c=0;c<32;c++){
        int i = t*32+c;
        s += W1[i]*as1[i]; d += W1[i]*ad1[i]; e += We1[i]*ae1[i]; e2 += We2[i]*ae2[i];
      }
      scal[16+t]=s; scal[24+t]=d; scal[32+t]=e; scal[40+t]=e2;
    }
  } else if (b == 2){
    for (int m = 32768 + t; m < 35904; m += 512){
      float v = 0.f;
      if (m >= 34816 && m < 34819) v = ew[wd[0]*3 + (m-34816)];
      else if (m >= 34819 && m < 34822) v = ec[cap[0]*3 + (m-34819)];
      else if (m >= 34822 && m < 34825) v = ev[veh[0]*3 + (m-34822)];
      wvec[m] = v;
    }
    __syncthreads();
    wvec[34825 + stops[t]] = 1.0f;     // 512 stops
  } else {
    int idx = (b-3)*512 + t;           // 32 blocks -> 16384
    int k = idx >> 6, r = idx & 63;
    Bcat[idx] = (r < 32) ? Wes[(size_t)k*32 + r] : Wes[(size_t)(256+k)*32 + (r-32)];
  }
}

__global__ void k_edges(const int* __restrict__ ei, const float* __restrict__ markov,
                        float* __restrict__ mark, int* __restrict__ deg){
  int e = blockIdx.x*256 + threadIdx.x;
  if (e >= NE) return;
  int s = ei[e], d = ei[NE+e];
  mark[e] = markov[(size_t)s*NN + d];
  atomicAdd(&deg[d], 1);
}

__global__ void k_scan(const int* deg, int* off, int* cur){
  __shared__ int tmp[NN];
  int t = threadIdx.x;
  tmp[t] = deg[t]; __syncthreads();
  for (int s=1; s<NN; s<<=1){
    int v = (t>=s) ? tmp[t-s] : 0;
    __syncthreads();
    tmp[t] += v;
    __syncthreads();
  }
  int ex = (t==0) ? 0 : tmp[t-1];
  off[t]=ex; cur[t]=ex;
  if (t==NN-1) off[NN]=tmp[NN-1];
}

__global__ void k_fill(const int* __restrict__ ei, int* __restrict__ cur, int* __restrict__ eidxl){
  int e = blockIdx.x*256 + threadIdx.x;
  if (e >= NE) return;
  int d = ei[NE+e];
  int p = atomicAdd(&cur[d], 1);
  eidxl[p] = e;
}

// ---------------- GAT layer 1 collapsed + x1 write (f32) ----------------
__global__ __launch_bounds__(64) void k_gat1x1(const int* __restrict__ ei, const int* __restrict__ eidxl,
    const int* __restrict__ off, const float* __restrict__ mark, const float* __restrict__ demand,
    const float* __restrict__ scal, const float* __restrict__ W1, const float* __restrict__ b1,
    float* __restrict__ x1){
  int n = blockIdx.x, lane = threadIdx.x;
  int o0 = off[n], o1 = off[n+1];
  float dn = demand[n];
  float cs[8], cd[8], ce[8], mx[8];
  #pragma unroll
  for (int h=0;h<8;h++){ cs[h]=scal[16+h]; cd[h]=scal[24+h]; ce[h]=scal[32+h]; mx[h]=-1e30f; }
  for (int i=o0+lane; i<o1; i+=64){
    int e = eidxl[i]; float ds = demand[ei[e]]; float me = mark[e];
    #pragma unroll
    for (int h=0;h<8;h++){
      float a = ds*cs[h] + dn*cd[h] + me*ce[h];
      a = a < 0.f ? 0.2f*a : a;
      mx[h] = fmaxf(mx[h], a);
    }
  }
  #pragma unroll
  for (int s=32; s>0; s>>=1){
    #pragma unroll
    for (int h=0;h<8;h++) mx[h] = fmaxf(mx[h], __shfl_xor(mx[h], s));
  }
  float se[8], sd_[8];
  #pragma unroll
  for (int h=0;h<8;h++){ se[h]=0.f; sd_[h]=0.f; }
  for (int i=o0+lane; i<o1; i+=64){
    int e = eidxl[i]; float ds = demand[ei[e]]; float me = mark[e];
    #pragma unroll
    for (int h=0;h<8;h++){
      float a = ds*cs[h] + dn*cd[h] + me*ce[h];
      a = a < 0.f ? 0.2f*a : a;
      float ex = expf(a - mx[h]);
      se[h] += ex; sd_[h] += ex*ds;
    }
  }
  #pragma unroll
  for (int s=32; s>0; s>>=1){
    #pragma unroll
    for (int h=0;h<8;h++){ se[h] += __shfl_xor(se[h], s); sd_[h] += __shfl_xor(sd_[h], s); }
  }
  float t1v[8];
  #pragma unroll
  for (int h=0;h<8;h++) t1v[h] = sd_[h] / (se[h] + 1e-16f);
  #pragma unroll
  for (int q=0;q<4;q++){
    int hc = lane + q*64; int h = hc >> 5;
    x1[(size_t)n*256 + hc] = fmaxf(t1v[h]*W1[hc] + b1[hc], 0.f);
  }
}

// ---------------- generic f32 GEMM (eab, with fused wvec epilogue) ----------------
__global__ __launch_bounds__(256) void gemm64(const float* __restrict__ A, int lda,
    const float* __restrict__ B, int ldb, float* __restrict__ C, int ldc, int K,
    float* __restrict__ wvec, const float* __restrict__ bes){
  __shared__ float As[16][68];
  __shared__ float Bs[16][68];
  int tid = threadIdx.x;
  int tx = tid & 15, ty = tid >> 4;
  int row0 = ty*4, col0 = tx*4;
  int gm = blockIdx.y*64, gn = blockIdx.x*64;
  float acc[4][4] = {};
  for (int k0 = 0; k0 < K; k0 += 16){
    #pragma unroll
    for (int q=0;q<4;q++){
      int idx = tid*4+q; int i = idx>>4, kk = idx&15;
      As[kk][i] = A[(size_t)(gm+i)*lda + k0 + kk];
    }
    #pragma unroll
    for (int q=0;q<4;q++){
      int idx = tid*4+q; int kk = idx>>6, j = idx&63;
      Bs[kk][j] = B[(size_t)(k0+kk)*ldb + gn + j];
    }
    __syncthreads();
    #pragma unroll
    for (int kk=0;kk<16;kk++){
      float a0=As[kk][row0+0], a1=As[kk][row0+1], a2=As[kk][row0+2], a3=As[kk][row0+3];
      float b0=Bs[kk][col0+0], b1=Bs[kk][col0+1], b2=Bs[kk][col0+2], b3=Bs[kk][col0+3];
      acc[0][0]+=a0*b0; acc[0][1]+=a0*b1; acc[0][2]+=a0*b2; acc[0][3]+=a0*b3;
      acc[1][0]+=a1*b0; acc[1][1]+=a1*b1; acc[1][2]+=a1*b2; acc[1][3]+=a1*b3;
      acc[2][0]+=a2*b0; acc[2][1]+=a2*b1; acc[2][2]+=a2*b2; acc[2][3]+=a2*b3;
      acc[3][0]+=a3*b0; acc[3][1]+=a3*b1; acc[3][2]+=a3*b2; acc[3][3]+=a3*b3;
    }
    __syncthreads();
  }
  #pragma unroll
  for (int i=0;i<4;i++){
    #pragma unroll
    for (int j=0;j<4;j++){
      int cc = gn + col0 + j;
      float v = acc[i][j];
      C[(size_t)(gm+row0+i)*ldc + cc] = v;
      if (wvec && cc >= 32){
        wvec[(size_t)(gm+row0+i)*32 + (cc-32)] = v + bes[cc-32];
      }
    }
  }
}

// ---------------- h2 epilogue fused with s2 dots (wave per node) ----------------
__global__ __launch_bounds__(64) void k_fin2s2(const float* __restrict__ P,
    const float* __restrict__ as2, const float* __restrict__ ad2,
    float* __restrict__ h2, float* __restrict__ s2s, float* __restrict__ s2d){
  int n = blockIdx.x, l = threadIdx.x;
  size_t off = (size_t)n*256 + l*4;
  float4 s = make_float4(0.f,0.f,0.f,0.f);
  #pragma unroll
  for (int p=0;p<8;p++){
    float4 v = *reinterpret_cast<const float4*>(P + ((size_t)p<<20) + off);
    s.x+=v.x; s.y+=v.y; s.z+=v.z; s.w+=v.w;
  }
  *reinterpret_cast<float4*>(h2 + off) = s;
  int c = l*4;
  float ss = s.x*as2[c]+s.y*as2[c+1]+s.z*as2[c+2]+s.w*as2[c+3];
  float sd = s.x*ad2[c]+s.y*ad2[c+1]+s.z*ad2[c+2]+s.w*ad2[c+3];
  #pragma unroll
  for (int sft=1; sft<8; sft<<=1){ ss += __shfl_xor(ss, sft); sd += __shfl_xor(sd, sft); }
  if ((l&7)==0){ s2s[n*8 + (l>>3)] = ss; s2d[n*8 + (l>>3)] = sd; }
}

// ---------------- fused layer-2 attention: max + denom + PV (block per node) ----------------
__global__ __launch_bounds__(256) void k_att2(const int* __restrict__ ei, const int* __restrict__ eidxl,
    const int* __restrict__ off, const float* __restrict__ mark, const float* __restrict__ s2s,
    const float* __restrict__ s2d, const float* __restrict__ scal,
    const float* __restrict__ h2, const float* __restrict__ b2, float* __restrict__ x2){
  __shared__ float red[256];
  __shared__ float mxL[8], invL[8], sdnL[8], ceL[8];
  __shared__ int eL[64], sL[64];
  __shared__ float cf[512];
  int n = blockIdx.x, tid = threadIdx.x;
  int el = tid >> 3, h = tid & 7;
  int o0 = off[n], o1 = off[n+1];
  if (tid < 8){ sdnL[tid] = s2d[n*8+tid]; ceL[tid] = scal[40+tid]; }
  __syncthreads();
  float sdn = sdnL[h], ce = ceL[h];
  // pass 1: max over edges (per head)
  float mx = -1e30f;
  for (int i=o0+el; i<o1; i+=32){
    int e = eidxl[i]; int s = ei[e]; float me = mark[e];
    float a = s2s[s*8+h] + sdn + me*ce;
    a = a < 0.f ? 0.2f*a : a;
    mx = fmaxf(mx, a);
  }
  red[tid] = mx; __syncthreads();
  for (int st=128; st>=8; st>>=1){
    if (tid < st) red[tid] = fmaxf(red[tid], red[tid+st]);
    __syncthreads();
  }
  if (tid < 8) mxL[tid] = red[tid];
  __syncthreads();
  float mxh = mxL[h];
  // pass 2: denom
  float se = 0.f;
  for (int i=o0+el; i<o1; i+=32){
    int e = eidxl[i]; int s = ei[e]; float me = mark[e];
    float a = s2s[s*8+h] + sdn + me*ce;
    a = a < 0.f ? 0.2f*a : a;
    se += expf(a - mxh);
  }
  red[tid] = se; __syncthreads();
  for (int st=128; st>=8; st>>=1){
    if (tid < st) red[tid] += red[tid+st];
    __syncthreads();
  }
  if (tid < 8) invL[tid] = 1.0f/(red[tid] + 1e-16f);
  __syncthreads();
  // pass 3: PV with coefficients recomputed into LDS
  int hcol = tid >> 5;
  float acc = 0.f;
  for (int b = o0; b < o1; b += 64){
    int len = min(64, o1 - b);
    __syncthreads();
    if (tid < len){ int e = eidxl[b+tid]; eL[tid] = e; sL[tid] = ei[e]; }
    __syncthreads();
    for (int idx = tid; idx < len*8; idx += 256){
      int j = idx >> 3, hh = idx & 7;
      float a = s2s[sL[j]*8+hh] + sdnL[hh] + mark[eL[j]]*ceL[hh];
      a = a < 0.f ? 0.2f*a : a;
      cf[idx] = expf(a - mxL[hh]);
    }
    __syncthreads();
    for (int j=0;j<len;j++){
      acc += cf[j*8 + hcol] * h2[(size_t)sL[j]*256 + tid];
    }
  }
  x2[(size_t)n*256 + tid] = fmaxf(acc*invL[hcol] + b2[tid], 0.f);
}

// ---------------- streaming pass over Wc1 (512-row chunks, grid 8x71) ----------------
__global__ __launch_bounds__(256) void k_src0(const float* __restrict__ Wc1, const float* __restrict__ wvec,
                                              float* __restrict__ srP, float* __restrict__ c0P){
  __shared__ float c0s[256*4];
  int t = threadIdx.x;
  int kg = t & 31;
  int rg = t >> 5;
  int col = blockIdx.x*128 + kg*4;
  int chunk = blockIdx.y;
  int m0 = chunk*512;
  float sr[4][4];
  #pragma unroll
  for (int u=0;u<4;u++){ sr[u][0]=0.f; sr[u][1]=0.f; sr[u][2]=0.f; sr[u][3]=0.f; }
  float c0a[4] = {0.f,0.f,0.f,0.f};
  for (int jj=0; jj<16; ++jj){
    int rbase = m0 + jj*32 + rg*4;
    #pragma unroll
    for (int u=0;u<4;u++){
      int m = rbase + u;
      float4 w = make_float4(0.f,0.f,0.f,0.f);
      float wv = 0.f;
      if (m < 35849){
        w = *reinterpret_cast<const float4*>(&Wc1[(size_t)m*1024 + col]);
        wv = wvec[m];
      }
      c0a[0] += wv*w.x; c0a[1] += wv*w.y; c0a[2] += wv*w.z; c0a[3] += wv*w.w;
      if (chunk < 64){
        sr[u][0] += w.x; sr[u][1] += w.y; sr[u][2] += w.z; sr[u][3] += w.w;
      }
    }
  }
  if (chunk < 64){
    #pragma unroll
    for (int u=0;u<4;u++){
      int r = rg*4 + u;
      float4 v = make_float4(sr[u][0], sr[u][1], sr[u][2], sr[u][3]);
      *reinterpret_cast<float4*>(&srP[(size_t)(chunk*32 + r)*1024 + col]) = v;
    }
  }
  c0s[t*4+0]=c0a[0]; c0s[t*4+1]=c0a[1]; c0s[t*4+2]=c0a[2]; c0s[t*4+3]=c0a[3];
  __syncthreads();
  if (t < 32){
    float s0=0.f,s1=0.f,s2=0.f,s3=0.f;
    #pragma unroll
    for (int q=0;q<8;q++){
      int b = (t + q*32)*4;
      s0 += c0s[b+0]; s1 += c0s[b+1]; s2 += c0s[b+2]; s3 += c0s[b+3];
    }
    float4 v = make_float4(s0,s1,s2,s3);
    *reinterpret_cast<float4*>(&c0P[(size_t)chunk*1024 + blockIdx.x*128 + t*4]) = v;
  }
}

__global__ void k_stage2(const float* __restrict__ srP, const float* __restrict__ c0P,
                         const float* __restrict__ bc1, float* __restrict__ Sr, float* __restrict__ base){
  int idx = blockIdx.x*256 + threadIdx.x;
  if (idx < 8192){
    int r = idx >> 8, k4 = idx & 255;
    float s0=0.f,s1=0.f,s2=0.f,s3=0.f;
    for (int c=0;c<64;c++){
      float4 v = *reinterpret_cast<const float4*>(&srP[(size_t)(c*32 + r)*1024 + k4*4]);
      s0+=v.x; s1+=v.y; s2+=v.z; s3+=v.w;
    }
    float4 o = make_float4(s0,s1,s2,s3);
    *reinterpret_cast<float4*>(&Sr[(size_t)r*1024 + k4*4]) = o;
  } else if (idx < 8448){
    int k4 = idx - 8192;
    float4 b = *reinterpret_cast<const float4*>(&bc1[k4*4]);
    float s0=b.x, s1=b.y, s2=b.z, s3=b.w;
    for (int c=0;c<71;c++){
      float4 v = *reinterpret_cast<const float4*>(&c0P[(size_t)c*1024 + k4*4]);
      s0+=v.x; s1+=v.y; s2+=v.z; s3+=v.w;
    }
    float4 o = make_float4(s0,s1,s2,s3);
    *reinterpret_cast<float4*>(&base[k4*4]) = o;
  }
}

__global__ void k_cvtT(const float* __restrict__ src, const float* __restrict__ src2, int k2,
                       int lds, int ldt, unsigned short* __restrict__ Th, unsigned short* __restrict__ Tl){
  cvtT_body(src, src2, k2, lds, ldt, Th, Tl, blockIdx.x*32, blockIdx.y*64, threadIdx.x);
}

// ---------------- split-bf16 MFMA GEMM, 128x128 tile, split-K planes ----------------
// A read as f32 (MODE 0: plain row-major Af/lda; MODE 1: composite [distn|markov|ea]),
// converted to bf16 hi/lo in registers during staging. B pre-transposed hi/lo.
template<int MODE>
__global__ __launch_bounds__(256) void k_mfma128(
    const float* __restrict__ Af, int lda,
    const float* __restrict__ dist, const float* __restrict__ markov,
    const float* __restrict__ eab, const float* __restrict__ scal,
    const unsigned short* __restrict__ Bth, const unsigned short* __restrict__ Btl, int ldb,
    float* __restrict__ Cp, int ldc, int kSteps, int kTot){
  __shared__ __align__(16) unsigned short Ash[128*32], Asl[128*32], Bsh[128*32], Bsl[128*32];
  int t = threadIdx.x;
  int wave = t >> 6, lane = t & 63;
  int wr = wave >> 1, wc = wave & 1;
  int gm = blockIdx.y*128, gn = blockIdx.x*128;
  float* plane = Cp + ((size_t)blockIdx.z << 20);
  int ks0 = blockIdx.z * kSteps;
  int ks1 = ks0 + kSteps; if (ks1 > kTot) ks1 = kTot;

  float mn = 0.f, nrm = 0.f;
  if (MODE == 1){ mn = scal[0]; nrm = scal[1]; }

  int kq = lane >> 4;
  int l15 = lane & 15;
  int r0s = t >> 2,        s0s = t & 3;
  int r1s = (t+256) >> 2,  s1s = t & 3;

  v4f acc[4][4];
  #pragma unroll
  for (int i=0;i<4;i++)
    #pragma unroll
    for (int j=0;j<4;j++) acc[i][j] = (v4f){0.f,0.f,0.f,0.f};

  for (int ks = ks0; ks < ks1; ++ks){
    int kb = ks*32;
    // A: load 8 f32 per (row, slot), two rows per thread
    float va[2][8];
    #pragma unroll
    for (int rr=0; rr<2; rr++){
      int r = rr ? r1s : r0s;
      int gi = gm + r;
      int kk = kb + (t&3)*8;
      const float* src;
      if (MODE == 0){
        src = Af + (size_t)gi*lda + kk;
      } else {
        if (kk < 1024)       src = dist   + (size_t)gi*1024 + kk;
        else if (kk < 2048)  src = markov + (size_t)gi*1024 + (kk-1024);
        else                 src = eab    + (size_t)gi*64   + (kk-2048);
      }
      float4 p0 = *reinterpret_cast<const float4*>(src);
      float4 p1 = *reinterpret_cast<const float4*>(src+4);
      va[rr][0]=p0.x; va[rr][1]=p0.y; va[rr][2]=p0.z; va[rr][3]=p0.w;
      va[rr][4]=p1.x; va[rr][5]=p1.y; va[rr][6]=p1.z; va[rr][7]=p1.w;
      if (MODE == 1 && kk < 1024){
        #pragma unroll
        for (int j=0;j<8;j++) va[rr][j] = (va[rr][j]-mn)*nrm;
      }
    }
    // B: hi/lo preconverted
    const size_t b0 = (size_t)(gn+r0s)*ldb + kb + s0s*8;
    const size_t b1 = (size_t)(gn+r1s)*ldb + kb + s1s*8;
    v8s gbh0 = *(const v8s*)(Bth + b0), gbh1 = *(const v8s*)(Bth + b1);
    v8s gbl0 = *(const v8s*)(Btl + b0), gbl1 = *(const v8s*)(Btl + b1);
    // convert A to hi/lo
    v8s gah[2], gal[2];
    #pragma unroll
    for (int rr=0; rr<2; rr++){
      #pragma unroll
      for (int j=0;j<8;j++){
        unsigned short hh = f2bf(va[rr][j]);
        gah[rr][j] = (short)hh;
        gal[rr][j] = (short)f2bf(va[rr][j] - bf2f(hh));
      }
    }
    __syncthreads();
    int w0 = r0s*32 + ((s0s ^ ((r0s>>1)&3))*8);
    int w1 = r1s*32 + ((s1s ^ ((r1s>>1)&3))*8);
    *(v8s*)(Ash + w0) = gah[0];  *(v8s*)(Ash + w1) = gah[1];
    *(v8s*)(Asl + w0) = gal[0];  *(v8s*)(Asl + w1) = gal[1];
    *(v8s*)(Bsh + w0) = gbh0;    *(v8s*)(Bsh + w1) = gbh1;
    *(v8s*)(Bsl + w0) = gbl0;    *(v8s*)(Bsl + w1) = gbl1;
    __syncthreads();
    v8s fbh[4], fbl[4];
    #pragma unroll
    for (int fj=0; fj<4; fj++){
      int cb = wc*64 + fj*16 + l15;
      int boff = cb*32 + ((kq ^ ((cb>>1)&3))*8);
      fbh[fj] = *(v8s*)(Bsh + boff);
      fbl[fj] = *(v8s*)(Bsl + boff);
    }
    #pragma unroll
    for (int fi=0; fi<4; fi++){
      int ra = wr*64 + fi*16 + l15;
      int aoff = ra*32 + ((kq ^ ((ra>>1)&3))*8);
      v8s fah = *(v8s*)(Ash + aoff);
      v8s fal = *(v8s*)(Asl + aoff);
      #pragma unroll
      for (int fj=0; fj<4; fj++){
        acc[fi][fj] = __builtin_amdgcn_mfma_f32_16x16x32_bf16(fah, fbh[fj], acc[fi][fj], 0, 0, 0);
        acc[fi][fj] = __builtin_amdgcn_mfma_f32_16x16x32_bf16(fah, fbl[fj], acc[fi][fj], 0, 0, 0);
        acc[fi][fj] = __builtin_amdgcn_mfma_f32_16x16x32_bf16(fal, fbh[fj], acc[fi][fj], 0, 0, 0);
      }
    }
  }
  int row0 = gm + wr*64 + (lane>>4)*4;
  int col0 = gn + wc*64 + l15;
  #pragma unroll
  for (int fi=0; fi<4; fi++)
    #pragma unroll
    for (int fj=0; fj<4; fj++)
      #pragma unroll
      for (int r=0; r<4; r++)
        plane[(size_t)(row0 + fi*16 + r)*ldc + col0 + fj*16] = acc[fi][fj][r];
}

// ---------------- epilogues (8 planes) ----------------
__global__ void k_fin_hidden(const float* __restrict__ P, const float* __restrict__ base,
                             float* __restrict__ hid){
  int idx = blockIdx.x*256 + threadIdx.x;
  float4 s = *reinterpret_cast<const float4*>(base + ((idx & 255)*4));
  #pragma unroll
  for (int p=0;p<8;p++){
    float4 v = *reinterpret_cast<const float4*>(P + ((size_t)p<<20) + (size_t)idx*4);
    s.x+=v.x; s.y+=v.y; s.z+=v.z; s.w+=v.w;
  }
  float4 o = make_float4(fmaxf(s.x,0.f), fmaxf(s.y,0.f), fmaxf(s.z,0.f), fmaxf(s.w,0.f));
  *reinterpret_cast<float4*>(hid + (size_t)idx*4) = o;
}

__global__ void k_fin_out(const float* __restrict__ P, const float* __restrict__ bc2,
                          float* __restrict__ out){
  int idx = blockIdx.x*256 + threadIdx.x;
  float4 s = *reinterpret_cast<const float4*>(bc2 + ((idx & 255)*4));
  #pragma unroll
  for (int p=0;p<8;p++){
    float4 v = *reinterpret_cast<const float4*>(P + ((size_t)p<<20) + (size_t)idx*4);
    s.x+=v.x; s.y+=v.y; s.z+=v.z; s.w+=v.w;
  }
  *reinterpret_cast<float4*>(out + (size_t)idx*4) = s;
}

// ---------------- launcher ----------------
extern "C" void kernel_launch(void* const* d_in, const int* in_sizes, int n_in,
                              void* d_out, int out_size, void* d_ws, size_t ws_size,
                              hipStream_t stream){
  const float* dist     = (const float*)d_in[0];
  const int*   stops    = (const int*)  d_in[1];
  const int*   weekday  = (const int*)  d_in[2];
  const int*   vehicles = (const int*)  d_in[3];
  const float* markov   = (const float*)d_in[4];
  const float* demand   = (const float*)d_in[5];
  const int*   capacity = (const int*)  d_in[6];
  const int*   ei       = (const int*)  d_in[7];
  const float* W1  = (const float*)d_in[8];
  const float* We1 = (const float*)d_in[9];
  const float* as1 = (const float*)d_in[10];
  const float* ad1 = (const float*)d_in[11];
  const float* ae1 = (const float*)d_in[12];
  const float* b1  = (const float*)d_in[13];
  const float* W2  = (const float*)d_in[14];
  const float* We2 = (const float*)d_in[15];
  const float* as2 = (const float*)d_in[16];
  const float* ad2 = (const float*)d_in[17];
  const float* ae2 = (const float*)d_in[18];
  const float* b2  = (const float*)d_in[19];
  const float* Wes = (const float*)d_in[20];
  const float* bes = (const float*)d_in[21];
  const float* ew  = (const float*)d_in[22];
  const float* ec  = (const float*)d_in[23];
  const float* ev  = (const float*)d_in[24];
  const float* Wc1 = (const float*)d_in[25];
  const float* bc1 = (const float*)d_in[26];
  const float* Wc2 = (const float*)d_in[27];
  const float* bc2 = (const float*)d_in[28];

  float* W    = (float*)d_ws;
  float* scal = W + OF_SCAL;
  float* mmP  = W + OF_MMP;
  int*   deg  = (int*)(W + OF_DEG);
  int*   off  = (int*)(W + OF_OFF);
  int*   cur  = (int*)(W + OF_CUR);
  int*   eidxl= (int*)(W + OF_EIDX);
  float* mark = W + OF_MARK;
  float* x1   = W + OF_X1;
  float* h2   = W + OF_H2;
  float* s2s  = W + OF_S2S;
  float* s2d  = W + OF_S2D;
  float* x2   = W + OF_X2;
  float* Bcat = W + OF_BCAT;
  float* eab  = W + OF_EAB;
  float* wvec = W + OF_WVEC;
  float* srP  = W + OF_SRP;
  float* c0P  = W + OF_C0P;
  float* Sr   = W + OF_SR;
  float* base = W + OF_BASE;
  unsigned short* Bth   = (unsigned short*)(W + OF_BTH);
  unsigned short* Btl   = (unsigned short*)(W + OF_BTL);
  float* hid  = W + OF_HID;
  unsigned short* W2th  = (unsigned short*)(W + OF_W2TH);
  unsigned short* W2tl  = (unsigned short*)(W + OF_W2TL);
  unsigned short* Wc2th = (unsigned short*)(W + OF_WC2TH);
  unsigned short* Wc2tl = (unsigned short*)(W + OF_WC2TL);
  float* P0   = W + OF_P0;
  float* out  = (float*)d_out;

  k_mm1cvtW<<<dim3(1152), dim3(256), 0, stream>>>(dist, mmP, mmP+512, deg, W2, Wc2,
                                                  W2th, W2tl, Wc2th, Wc2tl);
  k_misc<<<dim3(35), dim3(512), 0, stream>>>(mmP, mmP+512, scal, W1, We1, as1, ad1, ae1, We2, ae2,
                                             ew, ec, ev, weekday, capacity, vehicles, stops, wvec, Wes, Bcat);
  k_edges<<<dim3(256), dim3(256), 0, stream>>>(ei, markov, mark, deg);
  k_scan<<<dim3(1), dim3(1024), 0, stream>>>(deg, off, cur);
  k_fill<<<dim3(256), dim3(256), 0, stream>>>(ei, cur, eidxl);
  k_gat1x1<<<dim3(1024), dim3(64), 0, stream>>>(ei, eidxl, off, mark, demand, scal, W1, b1, x1);
  // h2 = x1 @ W2 : M=1024, N=256, K=256, splitK=8
  k_mfma128<0><<<dim3(2,8,8), dim3(256), 0, stream>>>(x1, 256, nullptr, nullptr, nullptr, nullptr,
                                                      W2th, W2tl, 256, P0, 256, 1, 8);
  k_fin2s2<<<dim3(1024), dim3(64), 0, stream>>>(P0, as2, ad2, h2, s2s, s2d);
  k_att2<<<dim3(1024), dim3(256), 0, stream>>>(ei, eidxl, off, mark, s2s, s2d, scal, h2, b2, x2);
  gemm64<<<dim3(1,16), dim3(256), 0, stream>>>(x2, 256, Bcat, 64, eab, 64, 256, wvec, bes);
  k_src0<<<dim3(8,71), dim3(256), 0, stream>>>(Wc1, wvec, srP, c0P);
  k_stage2<<<dim3(33), dim3(256), 0, stream>>>(srP, c0P, bc1, Sr, base);
  k_cvtT<<<dim3(65,16), dim3(256), 0, stream>>>(Wc1 + (size_t)32768*1024, Sr, 2048, 1024, 2080, Bth, Btl);
  // hidden = relu(A @ B + base)  (composite A, splitK=8)
  k_mfma128<1><<<dim3(8,8,8), dim3(256), 0, stream>>>(nullptr, 0, dist, markov, eab, scal,
                                                      Bth, Btl, 2080, P0, 1024, 9, 65);
  k_fin_hidden<<<dim3(1024), dim3(256), 0, stream>>>(P0, base, hid);
  // out = hid @ Wc2 + bc2  (splitK=8)
  k_mfma128<0><<<dim3(8,8,8), dim3(256), 0, stream>>>(hid, 1024, nullptr, nullptr, nullptr, nullptr,
                                                      Wc2th, Wc2tl, 1024, P0, 1024, 4, 32);
  k_fin_out<<<dim3(1024), dim3(256), 0, stream>>>(P0, bc2, out);
}